// Round 1
// baseline (3438.931 us; speedup 1.0000x reference)
//
#include <hip/hip_runtime.h>
#include <hip/hip_bf16.h>

#define B_ 2
#define T_ 2048
#define D_ 1024
#define H_ 16
#define HD_ 64
#define TI 16
#define TJ 32
#define NTJ (T_ / TJ) /* 64 */

// ---------- bf16 pack/unpack helpers (RNE pack; unpack is a shift) ----------
__device__ __forceinline__ unsigned pack_bf16(float x, float y) {
  unsigned xb = __float_as_uint(x);
  unsigned yb = __float_as_uint(y);
  xb += 0x7fffu + ((xb >> 16) & 1u);
  yb += 0x7fffu + ((yb >> 16) & 1u);
  return (xb >> 16) | (yb & 0xffff0000u);
}
__device__ __forceinline__ float blo(unsigned u) { return __uint_as_float(u << 16); }
__device__ __forceinline__ float bhi(unsigned u) { return __uint_as_float(u & 0xffff0000u); }

// ---------- fp32 tiled GEMM + bias: Y[M,1024] = X[M,1024] @ W[1024,1024] + b ----------
// BM=BN=64, BK=16, 256 threads, 4x4 micro-tile per thread.
__global__ __launch_bounds__(256) void gemm_bias(const float* __restrict__ X,
                                                 const float* __restrict__ W,
                                                 const float* __restrict__ bias,
                                                 float* __restrict__ Y) {
  __shared__ float As[16][68];  // As[k][m] (transposed A tile)
  __shared__ float Bs[16][68];  // Bs[k][n]
  const int tid = threadIdx.x;
  const int m0 = blockIdx.y << 6, n0 = blockIdx.x << 6;
  const int tr = tid >> 4, tc = tid & 15;
  const int arow = tid >> 2, akc = (tid & 3) << 2;
  const int bk = tid >> 4, bnc = (tid & 15) << 2;
  float c[4][4] = {};
  for (int k0 = 0; k0 < D_; k0 += 16) {
    const float4 av = *(const float4*)&X[(size_t)(m0 + arow) * D_ + k0 + akc];
    const float4 bv = *(const float4*)&W[(size_t)(k0 + bk) * D_ + n0 + bnc];
    __syncthreads();  // previous iteration's LDS reads complete
    As[akc + 0][arow] = av.x;
    As[akc + 1][arow] = av.y;
    As[akc + 2][arow] = av.z;
    As[akc + 3][arow] = av.w;
    *(float4*)&Bs[bk][bnc] = bv;
    __syncthreads();
#pragma unroll
    for (int k = 0; k < 16; ++k) {
      const float4 a = *(const float4*)&As[k][tr << 2];
      const float4 b = *(const float4*)&Bs[k][tc << 2];
      const float a4[4] = {a.x, a.y, a.z, a.w};
      const float b4[4] = {b.x, b.y, b.z, b.w};
#pragma unroll
      for (int e = 0; e < 4; ++e)
#pragma unroll
        for (int f = 0; f < 4; ++f) c[e][f] += a4[e] * b4[f];
    }
  }
  const float4 bb = *(const float4*)&bias[n0 + (tc << 2)];
#pragma unroll
  for (int e = 0; e < 4; ++e) {
    float4 o;
    o.x = c[e][0] + bb.x;
    o.y = c[e][1] + bb.y;
    o.z = c[e][2] + bb.z;
    o.w = c[e][3] + bb.w;
    *(float4*)&Y[(size_t)(m0 + (tr << 2) + e) * D_ + n0 + (tc << 2)] = o;
  }
}

// ---------- per-j-tile column sums of V: Blk[b][t][d] = sum_{j in tile t} V[b,j,d] ----------
__global__ __launch_bounds__(256) void vblock_sum(const float* __restrict__ V,
                                                  float* __restrict__ Blk) {
  const int b = blockIdx.x >> 6;  // NTJ = 64 tiles per batch
  const int t = blockIdx.x & 63;
  const int d = threadIdx.x << 2;
  float4 s = {0.f, 0.f, 0.f, 0.f};
  for (int j = 0; j < TJ; ++j) {
    const float4 v = *(const float4*)&V[((size_t)b * T_ + t * TJ + j) * D_ + d];
    s.x += v.x;
    s.y += v.y;
    s.z += v.z;
    s.w += v.w;
  }
  *(float4*)&Blk[(size_t)(b * NTJ + t) * D_ + d] = s;
}

// ---------- suffix scan over tiles: Suf[b][t][d] = sum_{j >= t*TJ} V[b,j,d]; Suf[b][NTJ][d]=0 ----------
__global__ __launch_bounds__(256) void vsuffix(const float* __restrict__ Blk,
                                               float* __restrict__ Suf) {
  const int b = blockIdx.x >> 2;
  const int d = ((blockIdx.x & 3) << 8) + threadIdx.x;
  float s = 0.f;
  Suf[((size_t)b * (NTJ + 1) + NTJ) * D_ + d] = 0.f;
  for (int t = NTJ - 1; t >= 0; --t) {
    s += Blk[((size_t)b * NTJ + t) * D_ + d];
    Suf[((size_t)b * (NTJ + 1) + t) * D_ + d] = s;
  }
}

// ---------- fused attention with head-axis softmax ----------
// Workgroup = (i-tile of 16 rows, batch). Loops j-tiles (32 cols) up to diagonal.
// Per j-tile: stage K (bf16) -> scores S[h][ii][jj] -> head-softmax (pointwise in (i,j),
// masked -> 1/16) + stage V (bf16, reuses K buffer) -> PV accumulate.
// Masked region beyond the diagonal tile handled via (1/16)*Suf.
__global__ __launch_bounds__(256) void attn_fused(const float* __restrict__ Q,
                                                  const float* __restrict__ K,
                                                  const float* __restrict__ V,
                                                  const float* __restrict__ Suf,
                                                  float* __restrict__ AO) {
  const int b = blockIdx.y;
  const int i0 = blockIdx.x * TI;
  const int tid = threadIdx.x;

  __shared__ unsigned Qs[TI][514];   // bf16 pairs, row = 1024 cols (512 pairs) + pad 2
  __shared__ unsigned KVs[TJ][514];  // K tile, then reused for V tile
  __shared__ float S[H_][TI][36];    // scores -> weights

  // stage Q tile (bf16)
  for (int u = tid; u < TI * 512; u += 256) {
    const int row = u >> 9, cp = u & 511;
    const float2 q = *(const float2*)&Q[((size_t)b * T_ + i0 + row) * D_ + (cp << 1)];
    Qs[row][cp] = pack_bf16(q.x, q.y);
  }
  const int ai = tid >> 4, g = tid & 15;  // PV/output mapping: row ai, cols h*64+g*4..+4
  const int sii = tid >> 5, sjj = tid & 31;  // QK mapping (rows sii, sii+8)
  float acc[H_][4] = {};
  __syncthreads();

  const int jt_max = (i0 + TI - 1) / TJ;  // diagonal j-tile (inclusive)
  for (int jt = 0; jt <= jt_max; ++jt) {
    const int j0 = jt * TJ;
    // stage K tile (bf16)
    for (int u = tid; u < TJ * 512; u += 256) {
      const int row = u >> 9, cp = u & 511;
      const float2 kv = *(const float2*)&K[((size_t)b * T_ + j0 + row) * D_ + (cp << 1)];
      KVs[row][cp] = pack_bf16(kv.x, kv.y);
    }
    __syncthreads();
    // scores: S[h][ii][jj] = dot64(Q_h[i0+ii], K_h[j0+jj]) / 32
#pragma unroll
    for (int h = 0; h < H_; ++h) {
      float d0 = 0.f, d1 = 0.f;
#pragma unroll
      for (int cp = 0; cp < 32; cp += 2) {
        const uint2 ku = *(const uint2*)&KVs[sjj][(h << 5) + cp];
        const uint2 qa = *(const uint2*)&Qs[sii][(h << 5) + cp];
        const uint2 qb = *(const uint2*)&Qs[sii + 8][(h << 5) + cp];
        const float k0 = blo(ku.x), k1 = bhi(ku.x), k2 = blo(ku.y), k3 = bhi(ku.y);
        d0 += blo(qa.x) * k0 + bhi(qa.x) * k1 + blo(qa.y) * k2 + bhi(qa.y) * k3;
        d1 += blo(qb.x) * k0 + bhi(qb.x) * k1 + blo(qb.y) * k2 + bhi(qb.y) * k3;
      }
      S[h][sii][sjj] = d0 * 0.03125f;
      S[h][sii + 8][sjj] = d1 * 0.03125f;
    }
    __syncthreads();
    // stage V tile (bf16) into KVs (safe: all K reads done)
    for (int u = tid; u < TJ * 512; u += 256) {
      const int row = u >> 9, cp = u & 511;
      const float2 vv = *(const float2*)&V[((size_t)b * T_ + j0 + row) * D_ + (cp << 1)];
      KVs[row][cp] = pack_bf16(vv.x, vv.y);
    }
    // head-axis softmax, pointwise per (i,j); causal-masked -> uniform 1/16
    for (int p = tid; p < TI * TJ; p += 256) {
      const int pi = p >> 5, pj = p & 31;
      if ((j0 + pj) > (i0 + pi)) {
#pragma unroll
        for (int h = 0; h < H_; ++h) S[h][pi][pj] = 0.0625f;
      } else {
        float sv[H_];
        float m = -1e30f;
#pragma unroll
        for (int h = 0; h < H_; ++h) {
          sv[h] = S[h][pi][pj];
          m = fmaxf(m, sv[h]);
        }
        float sum = 0.f;
#pragma unroll
        for (int h = 0; h < H_; ++h) {
          sv[h] = __expf(sv[h] - m);
          sum += sv[h];
        }
        const float inv = 1.0f / sum;
#pragma unroll
        for (int h = 0; h < H_; ++h) S[h][pi][pj] = sv[h] * inv;
      }
    }
    __syncthreads();
    // PV: acc[h][0..3] += w[h][ai][jj] * V_h[jj][g*4..+4]
#pragma unroll
    for (int h = 0; h < H_; ++h) {
#pragma unroll 8
      for (int jj = 0; jj < TJ; ++jj) {
        const float w = S[h][ai][jj];
        const uint2 vv = *(const uint2*)&KVs[jj][(h << 5) + (g << 1)];
        acc[h][0] += w * blo(vv.x);
        acc[h][1] += w * bhi(vv.x);
        acc[h][2] += w * blo(vv.y);
        acc[h][3] += w * bhi(vv.y);
      }
    }
    __syncthreads();
  }
  // beyond-diagonal masked contribution: (1/16) * suffix-sum of V
  const float* sp = &Suf[((size_t)b * (NTJ + 1) + (jt_max + 1)) * D_];
#pragma unroll
  for (int h = 0; h < H_; ++h) {
    const int col = (h << 6) + (g << 2);
    const float4 s4 = *(const float4*)&sp[col];
    float4 o;
    o.x = acc[h][0] + 0.0625f * s4.x;
    o.y = acc[h][1] + 0.0625f * s4.y;
    o.z = acc[h][2] + 0.0625f * s4.z;
    o.w = acc[h][3] + 0.0625f * s4.w;
    *(float4*)&AO[((size_t)b * T_ + i0 + ai) * D_ + col] = o;
  }
}

extern "C" void kernel_launch(void* const* d_in, const int* in_sizes, int n_in,
                              void* d_out, int out_size, void* d_ws, size_t ws_size,
                              hipStream_t stream) {
  (void)in_sizes;
  (void)n_in;
  (void)out_size;
  (void)ws_size;
  const float* x = (const float*)d_in[0];
  const float* Wq = (const float*)d_in[1];
  const float* bq = (const float*)d_in[2];
  const float* Wk = (const float*)d_in[3];
  const float* bk = (const float*)d_in[4];
  const float* Wv = (const float*)d_in[5];
  const float* bv = (const float*)d_in[6];
  const float* Wo = (const float*)d_in[7];
  const float* bo = (const float*)d_in[8];
  float* out = (float*)d_out;
  float* ws = (float*)d_ws;

  const size_t SZ = (size_t)B_ * T_ * D_;  // 4,194,304 floats
  float* Qw = ws;
  float* Kw = ws + SZ;
  float* Vw = ws + 2 * SZ;
  float* AO = ws + 3 * SZ;
  float* Blk = ws + 4 * SZ;                       // B*NTJ*D
  float* Suf = Blk + (size_t)B_ * NTJ * D_;       // B*(NTJ+1)*D

  const dim3 gg(D_ / 64, (B_ * T_) / 64);
  const dim3 tb(256);
  hipLaunchKernelGGL(gemm_bias, gg, tb, 0, stream, x, Wq, bq, Qw);
  hipLaunchKernelGGL(gemm_bias, gg, tb, 0, stream, x, Wk, bk, Kw);
  hipLaunchKernelGGL(gemm_bias, gg, tb, 0, stream, x, Wv, bv, Vw);
  hipLaunchKernelGGL(vblock_sum, dim3(B_ * NTJ), tb, 0, stream, Vw, Blk);
  hipLaunchKernelGGL(vsuffix, dim3(B_ * 4), tb, 0, stream, Blk, Suf);
  hipLaunchKernelGGL(attn_fused, dim3(T_ / TI, B_), tb, 0, stream, Qw, Kw, Vw, Suf, AO);
  hipLaunchKernelGGL(gemm_bias, gg, tb, 0, stream, AO, Wo, bo, out);
}

// Round 2
// 935.946 us; speedup vs baseline: 3.6743x; 3.6743x over previous
//
#include <hip/hip_runtime.h>
#include <hip/hip_bf16.h>

#define B_ 2
#define T_ 2048
#define D_ 1024
#define H_ 16

typedef __attribute__((ext_vector_type(8))) short bf16x8;
typedef __attribute__((ext_vector_type(4))) float f32x4;

__device__ __forceinline__ unsigned pack_bf16(float x, float y) {
  unsigned xb = __float_as_uint(x), yb = __float_as_uint(y);
  xb += 0x7fffu + ((xb >> 16) & 1u);
  yb += 0x7fffu + ((yb >> 16) & 1u);
  return (xb >> 16) | (yb & 0xffff0000u);
}
__device__ __forceinline__ unsigned short f2b(float x) {
  unsigned u = __float_as_uint(x);
  u += 0x7fffu + ((u >> 16) & 1u);
  return (unsigned short)(u >> 16);
}
__device__ __forceinline__ float blo(unsigned u) { return __uint_as_float(u << 16); }
__device__ __forceinline__ float bhi(unsigned u) { return __uint_as_float(u & 0xffff0000u); }

// ---------- fp32 GEMM + bias -> bf16 output (projections) ----------
__global__ __launch_bounds__(256) void gemm_bias_b16(const float* __restrict__ X,
                                                     const float* __restrict__ W,
                                                     const float* __restrict__ bias,
                                                     unsigned short* __restrict__ Yb) {
  __shared__ float As[16][68];
  __shared__ float Bs[16][68];
  const int tid = threadIdx.x;
  const int m0 = blockIdx.y << 6, n0 = blockIdx.x << 6;
  const int tr = tid >> 4, tc = tid & 15;
  const int arow = tid >> 2, akc = (tid & 3) << 2;
  const int bk = tid >> 4, bnc = (tid & 15) << 2;
  float c[4][4] = {};
  for (int k0 = 0; k0 < D_; k0 += 16) {
    const float4 av = *(const float4*)&X[(size_t)(m0 + arow) * D_ + k0 + akc];
    const float4 bv = *(const float4*)&W[(size_t)(k0 + bk) * D_ + n0 + bnc];
    __syncthreads();
    As[akc + 0][arow] = av.x; As[akc + 1][arow] = av.y;
    As[akc + 2][arow] = av.z; As[akc + 3][arow] = av.w;
    *(float4*)&Bs[bk][bnc] = bv;
    __syncthreads();
#pragma unroll
    for (int k = 0; k < 16; ++k) {
      const float4 a = *(const float4*)&As[k][tr << 2];
      const float4 b = *(const float4*)&Bs[k][tc << 2];
      const float a4[4] = {a.x, a.y, a.z, a.w};
      const float b4[4] = {b.x, b.y, b.z, b.w};
#pragma unroll
      for (int e = 0; e < 4; ++e)
#pragma unroll
        for (int f = 0; f < 4; ++f) c[e][f] += a4[e] * b4[f];
    }
  }
  const float4 bb = *(const float4*)&bias[n0 + (tc << 2)];
#pragma unroll
  for (int e = 0; e < 4; ++e) {
    uint2 o;
    o.x = pack_bf16(c[e][0] + bb.x, c[e][1] + bb.y);
    o.y = pack_bf16(c[e][2] + bb.z, c[e][3] + bb.w);
    *(uint2*)&Yb[(size_t)(m0 + (tr << 2) + e) * D_ + n0 + (tc << 2)] = o;
  }
}

// ---------- fp32 GEMM + bias, A = A0 + A1 (final output) ----------
__global__ __launch_bounds__(256) void gemm_bias2(const float* __restrict__ A0,
                                                  const float* __restrict__ A1,
                                                  const float* __restrict__ W,
                                                  const float* __restrict__ bias,
                                                  float* __restrict__ Y) {
  __shared__ float As[16][68];
  __shared__ float Bs[16][68];
  const int tid = threadIdx.x;
  const int m0 = blockIdx.y << 6, n0 = blockIdx.x << 6;
  const int tr = tid >> 4, tc = tid & 15;
  const int arow = tid >> 2, akc = (tid & 3) << 2;
  const int bk = tid >> 4, bnc = (tid & 15) << 2;
  float c[4][4] = {};
  for (int k0 = 0; k0 < D_; k0 += 16) {
    const float4 a0 = *(const float4*)&A0[(size_t)(m0 + arow) * D_ + k0 + akc];
    const float4 a1 = *(const float4*)&A1[(size_t)(m0 + arow) * D_ + k0 + akc];
    const float4 bv = *(const float4*)&W[(size_t)(k0 + bk) * D_ + n0 + bnc];
    __syncthreads();
    As[akc + 0][arow] = a0.x + a1.x; As[akc + 1][arow] = a0.y + a1.y;
    As[akc + 2][arow] = a0.z + a1.z; As[akc + 3][arow] = a0.w + a1.w;
    *(float4*)&Bs[bk][bnc] = bv;
    __syncthreads();
#pragma unroll
    for (int k = 0; k < 16; ++k) {
      const float4 a = *(const float4*)&As[k][tr << 2];
      const float4 b = *(const float4*)&Bs[k][tc << 2];
      const float a4[4] = {a.x, a.y, a.z, a.w};
      const float b4[4] = {b.x, b.y, b.z, b.w};
#pragma unroll
      for (int e = 0; e < 4; ++e)
#pragma unroll
        for (int f = 0; f < 4; ++f) c[e][f] += a4[e] * b4[f];
    }
  }
  const float4 bb = *(const float4*)&bias[n0 + (tc << 2)];
#pragma unroll
  for (int e = 0; e < 4; ++e) {
    float4 o;
    o.x = c[e][0] + bb.x; o.y = c[e][1] + bb.y;
    o.z = c[e][2] + bb.z; o.w = c[e][3] + bb.w;
    *(float4*)&Y[(size_t)(m0 + (tr << 2) + e) * D_ + n0 + (tc << 2)] = o;
  }
}

// ---------- bf16 transpose: Vb [b][t][d] -> Vt [b][d][t] ----------
__global__ __launch_bounds__(256) void transpose_bf16(const unsigned short* __restrict__ Vb,
                                                      unsigned short* __restrict__ Vt) {
  __shared__ unsigned short tile[64][73];
  const int b = blockIdx.z;
  const int t0 = blockIdx.x << 6, d0 = blockIdx.y << 6;
  const int row = threadIdx.x >> 2, cq = (threadIdx.x & 3) << 4;
  const unsigned short* src = &Vb[((size_t)((b << 11) + t0 + row) << 10) + d0 + cq];
  const uint4 va = *(const uint4*)&src[0];
  const uint4 vb2 = *(const uint4*)&src[8];
  const unsigned in[8] = {va.x, va.y, va.z, va.w, vb2.x, vb2.y, vb2.z, vb2.w};
#pragma unroll
  for (int e = 0; e < 8; ++e) {
    tile[row][cq + 2 * e] = (unsigned short)in[e];
    tile[row][cq + 2 * e + 1] = (unsigned short)(in[e] >> 16);
  }
  __syncthreads();
  unsigned o[8];
#pragma unroll
  for (int e = 0; e < 8; ++e)
    o[e] = (unsigned)tile[cq + 2 * e][row] | ((unsigned)tile[cq + 2 * e + 1][row] << 16);
  unsigned short* dst = &Vt[((size_t)((b << 10) + d0 + row) << 11) + t0 + cq];
  uint4 lo, hi;
  lo.x = o[0]; lo.y = o[1]; lo.z = o[2]; lo.w = o[3];
  hi.x = o[4]; hi.y = o[5]; hi.z = o[6]; hi.w = o[7];
  *(uint4*)&dst[0] = lo;
  *(uint4*)&dst[8] = hi;
}

// ---------- per-128-row block sums of V (bf16 in, fp32 out) ----------
__global__ __launch_bounds__(256) void vblk(const unsigned short* __restrict__ Vb,
                                            float* __restrict__ Blk) {
  const int b = blockIdx.x >> 4, bt = blockIdx.x & 15;
  const int d4 = threadIdx.x << 2;
  float s0 = 0.f, s1 = 0.f, s2 = 0.f, s3 = 0.f;
  for (int j = 0; j < 128; ++j) {
    const uint2 v = *(const uint2*)&Vb[((size_t)((b << 11) + (bt << 7) + j) << 10) + d4];
    s0 += blo(v.x); s1 += bhi(v.x); s2 += blo(v.y); s3 += bhi(v.y);
  }
  float4 o = {s0, s1, s2, s3};
  *(float4*)&Blk[((size_t)((b << 4) + bt) << 10) + d4] = o;
}

// ---------- suffix over 16 blocks: Suf[b][bt][d] = sum_{bt'>=bt} Blk; Suf[b][16][d]=0 ----------
__global__ __launch_bounds__(256) void vsuffix16(const float* __restrict__ Blk,
                                                 float* __restrict__ Suf) {
  const int idx = blockIdx.x * 256 + threadIdx.x;
  const int b = idx >> 10, d = idx & 1023;
  float s = 0.f;
  Suf[((size_t)(b * 17 + 16) << 10) + d] = 0.f;
  for (int bt = 15; bt >= 0; --bt) {
    s += Blk[((size_t)((b << 4) + bt) << 10) + d];
    Suf[((size_t)(b * 17 + bt) << 10) + d] = s;
  }
}

// ---------- MFMA fused attention, head-axis softmax ----------
// 8 waves. i-tile=16 rows, j-step=128 (wave w owns j-sub [16w,16w+16) for QK; heads {2w,2w+1} for PV).
// Softmax lane-local (C-layout packs all 16 head scores per (i,j) in one lane).
// W relayout via 32KB XOR-swizzled LDS in two 64-j phases. Beyond-diagonal mass = Suf/16.
// j-range split across 2 blocks (hf) writing AO0/AO1; summed in final GEMM.
#define QIDX(i, d) ((((i) << 10) + (d)) ^ (((i)&7) << 3))
#define WIDX(h, i, j) (((((h) << 4) + (i)) << 6) + (j)) ^ (((i)&7) << 3)
__global__ __launch_bounds__(512, 2) void attn_mfma(const unsigned short* __restrict__ Qb,
                                                    const unsigned short* __restrict__ Kb,
                                                    const unsigned short* __restrict__ Vt,
                                                    const float* __restrict__ Suf,
                                                    float* __restrict__ AO0,
                                                    float* __restrict__ AO1) {
  __shared__ unsigned short Qs[16 * 1024];   // 32 KB, row-XOR-swizzled
  __shared__ unsigned short Ws[16 * 16 * 64]; // 32 KB, [h][i][j64], XOR-swizzled

  const int bx = blockIdx.x;
  const int it = 127 - (bx >> 2);       // heavy-first
  const int bb = bx & 1;
  const int hf = (bx >> 1) & 1;
  const int i0 = it << 4;
  const int jtmax = it >> 3;
  const int niters = jtmax + 1, n0 = niters >> 1;
  const int jt_lo = hf ? n0 : 0;
  const int jt_hi = hf ? niters : n0;

  const int tid = threadIdx.x;
  const int w = tid >> 6, l = tid & 63;
  const int g = l >> 4, c = l & 15;

  // stage Q tile (bf16, swizzled)
  for (int u = tid; u < 2048; u += 512) {
    const int i = u >> 7, dc = (u & 127) << 3;
    const uint4 v = *(const uint4*)&Qb[((size_t)((bb << 11) + i0 + i) << 10) + dc];
    *(uint4*)&Qs[QIDX(i, dc)] = v;
  }

  f32x4 accPV[2][4];
#pragma unroll
  for (int hh = 0; hh < 2; ++hh)
#pragma unroll
    for (int cc = 0; cc < 4; ++cc) accPV[hh][cc] = {0.f, 0.f, 0.f, 0.f};

  __syncthreads();

  for (int jt = jt_lo; jt < jt_hi; ++jt) {
    const int j0 = jt << 7;
    const int jw = j0 + (w << 4);  // wave's j-base
    f32x4 acc[16];
    const bool live = (jw <= i0 + 15);
    if (live) {
#pragma unroll
      for (int h = 0; h < 16; ++h) acc[h] = {0.f, 0.f, 0.f, 0.f};
      const unsigned short* kbase = &Kb[((size_t)((bb << 11) + jw + c) << 10)];
#pragma unroll
      for (int h = 0; h < 16; ++h) {
        const bf16x8 k0 = *(const bf16x8*)&kbase[(h << 6) + (g << 3)];
        const bf16x8 k1 = *(const bf16x8*)&kbase[(h << 6) + 32 + (g << 3)];
        const bf16x8 q0 = *(const bf16x8*)&Qs[QIDX(c, (h << 6) + (g << 3))];
        const bf16x8 q1 = *(const bf16x8*)&Qs[QIDX(c, (h << 6) + 32 + (g << 3))];
        acc[h] = __builtin_amdgcn_mfma_f32_16x16x32_bf16(q0, k0, acc[h], 0, 0, 0);
        acc[h] = __builtin_amdgcn_mfma_f32_16x16x32_bf16(q1, k1, acc[h], 0, 0, 0);
      }
      // head-axis softmax, lane-local; masked -> 1/16
#pragma unroll
      for (int r = 0; r < 4; ++r) {
        float ex[16];
        float sum = 0.f;
#pragma unroll
        for (int h = 0; h < 16; ++h) {
          ex[h] = exp2f(acc[h][r] * 0.04508422f);  // (1/32)*log2(e)
          sum += ex[h];
        }
        const float inv = 1.0f / sum;
        const bool msk = (jw + c) > (i0 + (g << 2) + r);
#pragma unroll
        for (int h = 0; h < 16; ++h) acc[h][r] = msk ? 0.0625f : ex[h] * inv;
      }
    } else {
#pragma unroll
      for (int h = 0; h < 16; ++h) acc[h] = {0.0625f, 0.0625f, 0.0625f, 0.0625f};
    }

    // two PV phases (64 j each) through the 32KB Ws buffer
#pragma unroll
    for (int p = 0; p < 2; ++p) {
      __syncthreads();  // previous phase's reads done
      if ((w >> 2) == p) {
#pragma unroll
        for (int h = 0; h < 16; ++h)
#pragma unroll
          for (int r = 0; r < 4; ++r) {
            const int i = (g << 2) + r;
            Ws[WIDX(h, i, ((w & 3) << 4) + c)] = f2b(acc[h][r]);
          }
      }
      __syncthreads();
#pragma unroll
      for (int hh = 0; hh < 2; ++hh) {
        const int h = (w << 1) + hh;
        const unsigned short* vbase = &Vt[((size_t)((bb << 10) + (h << 6)) << 11)];
#pragma unroll
        for (int ks = 0; ks < 2; ++ks) {
          const bf16x8 a = *(const bf16x8*)&Ws[WIDX(h, c, (ks << 5) + (g << 3))];
          const int jcol = j0 + (p << 6) + (ks << 5) + (g << 3);
#pragma unroll
          for (int cc = 0; cc < 4; ++cc) {
            const bf16x8 bv =
                *(const bf16x8*)&vbase[((size_t)((cc << 4) + c) << 11) + jcol];
            accPV[hh][cc] =
                __builtin_amdgcn_mfma_f32_16x16x32_bf16(a, bv, accPV[hh][cc], 0, 0, 0);
          }
        }
      }
    }
  }

  // epilogue: suffix (half 1 only) + store
  float* AOt = hf ? AO1 : AO0;
  const float* sufrow = &Suf[((size_t)(bb * 17 + jtmax + 1) << 10)];
#pragma unroll
  for (int hh = 0; hh < 2; ++hh) {
    const int h = (w << 1) + hh;
#pragma unroll
    for (int cc = 0; cc < 4; ++cc) {
      const int d = (h << 6) + (cc << 4) + c;
      const float sadd = hf ? 0.0625f * sufrow[d] : 0.0f;
#pragma unroll
      for (int r = 0; r < 4; ++r) {
        AOt[((size_t)((bb << 11) + i0 + (g << 2) + r) << 10) + d] = accPV[hh][cc][r] + sadd;
      }
    }
  }
}

extern "C" void kernel_launch(void* const* d_in, const int* in_sizes, int n_in,
                              void* d_out, int out_size, void* d_ws, size_t ws_size,
                              hipStream_t stream) {
  (void)in_sizes; (void)n_in; (void)out_size; (void)ws_size;
  const float* x = (const float*)d_in[0];
  const float* Wq = (const float*)d_in[1];
  const float* bq = (const float*)d_in[2];
  const float* Wk = (const float*)d_in[3];
  const float* bk = (const float*)d_in[4];
  const float* Wv = (const float*)d_in[5];
  const float* bv = (const float*)d_in[6];
  const float* Wo = (const float*)d_in[7];
  const float* bo = (const float*)d_in[8];
  float* out = (float*)d_out;
  char* ws = (char*)d_ws;

  const size_t MB = 1024 * 1024;
  unsigned short* Qb = (unsigned short*)(ws);
  unsigned short* Kb = (unsigned short*)(ws + 8 * MB);
  unsigned short* Vb = (unsigned short*)(ws + 16 * MB);
  unsigned short* Vt = (unsigned short*)(ws + 24 * MB);
  float* AO0 = (float*)(ws + 32 * MB);
  float* AO1 = (float*)(ws + 48 * MB);
  float* Blk = (float*)(ws + 64 * MB);                    // 2*16*1024*4 = 128 KB
  float* Suf = (float*)(ws + 64 * MB + 256 * 1024);       // 2*17*1024*4 ≈ 136 KB

  const dim3 gg(D_ / 64, (B_ * T_) / 64);
  const dim3 tb(256);
  hipLaunchKernelGGL(gemm_bias_b16, gg, tb, 0, stream, x, Wq, bq, Qb);
  hipLaunchKernelGGL(gemm_bias_b16, gg, tb, 0, stream, x, Wk, bk, Kb);
  hipLaunchKernelGGL(gemm_bias_b16, gg, tb, 0, stream, x, Wv, bv, Vb);
  hipLaunchKernelGGL(transpose_bf16, dim3(32, 16, B_), tb, 0, stream, Vb, Vt);
  hipLaunchKernelGGL(vblk, dim3(B_ * 16), tb, 0, stream, Vb, Blk);
  hipLaunchKernelGGL(vsuffix16, dim3(8), tb, 0, stream, Blk, Suf);
  hipLaunchKernelGGL(attn_mfma, dim3(512), dim3(512), 0, stream, Qb, Kb, Vt, Suf, AO0, AO1);
  hipLaunchKernelGGL(gemm_bias2, gg, tb, 0, stream, AO0, AO1, Wo, bo, out);
}

// Round 3
// 648.396 us; speedup vs baseline: 5.3038x; 1.4435x over previous
//
#include <hip/hip_runtime.h>
#include <hip/hip_bf16.h>

#define B_ 2
#define T_ 2048
#define D_ 1024
#define H_ 16

typedef __attribute__((ext_vector_type(8))) short bf16x8;
typedef __attribute__((ext_vector_type(4))) float f32x4;

__device__ __forceinline__ unsigned pack_bf16(float x, float y) {
  unsigned xb = __float_as_uint(x), yb = __float_as_uint(y);
  xb += 0x7fffu + ((xb >> 16) & 1u);
  yb += 0x7fffu + ((yb >> 16) & 1u);
  return (xb >> 16) | (yb & 0xffff0000u);
}
__device__ __forceinline__ unsigned short f2b(float x) {
  unsigned u = __float_as_uint(x);
  u += 0x7fffu + ((u >> 16) & 1u);
  return (unsigned short)(u >> 16);
}
__device__ __forceinline__ float blo(unsigned u) { return __uint_as_float(u << 16); }
__device__ __forceinline__ float bhi(unsigned u) { return __uint_as_float(u & 0xffff0000u); }

__device__ __forceinline__ void gld_lds16(const unsigned short* g, unsigned short* l) {
  __builtin_amdgcn_global_load_lds(
      (const __attribute__((address_space(1))) unsigned int*)g,
      (__attribute__((address_space(3))) unsigned int*)l, 16, 0, 0);
}

// ---------- weight transpose + convert: Wt[n][k] = bf16(W[k][n]), 4 weights ----------
__global__ __launch_bounds__(256) void wtrans(const float* __restrict__ W0, const float* __restrict__ W1,
                                              const float* __restrict__ W2, const float* __restrict__ W3,
                                              unsigned short* __restrict__ T0, unsigned short* __restrict__ T1,
                                              unsigned short* __restrict__ T2, unsigned short* __restrict__ T3) {
  const int z = blockIdx.z;
  const float* W = z == 0 ? W0 : z == 1 ? W1 : z == 2 ? W2 : W3;
  unsigned short* T = z == 0 ? T0 : z == 1 ? T1 : z == 2 ? T2 : T3;
  __shared__ unsigned short t[64][72];
  const int k0 = blockIdx.x << 6, n0 = blockIdx.y << 6;
  const int r = threadIdx.x >> 2, c16 = (threadIdx.x & 3) << 4;
#pragma unroll
  for (int e = 0; e < 4; ++e) {
    const float4 v = *(const float4*)&W[(size_t)(k0 + r) * 1024 + n0 + c16 + e * 4];
    t[r][c16 + e * 4 + 0] = f2b(v.x);
    t[r][c16 + e * 4 + 1] = f2b(v.y);
    t[r][c16 + e * 4 + 2] = f2b(v.z);
    t[r][c16 + e * 4 + 3] = f2b(v.w);
  }
  __syncthreads();
  unsigned short o[16];
#pragma unroll
  for (int e = 0; e < 16; ++e) o[e] = t[c16 + e][r];
  unsigned short* dst = &T[(size_t)(n0 + r) * 1024 + k0 + c16];
  *(uint4*)&dst[0] = *(uint4*)&o[0];
  *(uint4*)&dst[8] = *(uint4*)&o[8];
}

// ---------- x fp32 -> bf16 ----------
__global__ __launch_bounds__(256) void xconv(const float* __restrict__ x, unsigned short* __restrict__ xb) {
  const int i = (blockIdx.x * 256 + threadIdx.x) * 8;
  const float4 a = *(const float4*)&x[i];
  const float4 b = *(const float4*)&x[i + 4];
  uint4 o;
  o.x = pack_bf16(a.x, a.y);
  o.y = pack_bf16(a.z, a.w);
  o.z = pack_bf16(b.x, b.y);
  o.w = pack_bf16(b.z, b.w);
  *(uint4*)&xb[i] = o;
}

// ---------- bf16 MFMA GEMM: Y = A[M,1024] @ Bt[n][k]^T + bias ----------
// 128x128 tile, BK=64, 4 waves (2x2 of 64x64), global_load_lds w16, XOR-swizzled LDS.
template <bool BF16OUT>
__global__ __launch_bounds__(256) void gemm_mfma(const unsigned short* __restrict__ A,
                                                 const unsigned short* __restrict__ B0,
                                                 const unsigned short* __restrict__ B1,
                                                 const unsigned short* __restrict__ B2,
                                                 const float* __restrict__ bi0, const float* __restrict__ bi1,
                                                 const float* __restrict__ bi2,
                                                 void* __restrict__ Y0, void* __restrict__ Y1,
                                                 void* __restrict__ Y2) {
  const int z = blockIdx.z;
  const unsigned short* Bt = z == 0 ? B0 : z == 1 ? B1 : B2;
  const float* bias = z == 0 ? bi0 : z == 1 ? bi1 : bi2;
  void* Y = z == 0 ? Y0 : z == 1 ? Y1 : Y2;
  __shared__ unsigned short As[8192];
  __shared__ unsigned short Bs[8192];
  const int tid = threadIdx.x;
  const int m0 = blockIdx.y << 7, n0 = blockIdx.x << 7;
  const int w = tid >> 6, l = tid & 63, g = l >> 4, c = l & 15;
  const int wm = (w >> 1) << 6, wn = (w & 1) << 6;
  const int srow = tid >> 3;
  const int skel = ((tid & 7) ^ (srow & 7)) << 3;  // inverse-swizzled k-element
  const unsigned short* ga = &A[(size_t)(m0 + srow) * 1024 + skel];
  const unsigned short* gb = &Bt[(size_t)(n0 + srow) * 1024 + skel];
  unsigned short* la = &As[tid << 3];
  unsigned short* lb = &Bs[tid << 3];
  f32x4 acc[4][4];
#pragma unroll
  for (int i = 0; i < 4; ++i)
#pragma unroll
    for (int j = 0; j < 4; ++j) acc[i][j] = {0.f, 0.f, 0.f, 0.f};
  for (int k0 = 0; k0 < 1024; k0 += 64) {
    __syncthreads();
#pragma unroll
    for (int a = 0; a < 4; ++a) {
      gld_lds16(ga + (size_t)(a << 5) * 1024 + k0, la + (a << 11));
      gld_lds16(gb + (size_t)(a << 5) * 1024 + k0, lb + (a << 11));
    }
    __syncthreads();
#pragma unroll
    for (int kc = 0; kc < 2; ++kc) {
      bf16x8 af[4], bfr[4];
#pragma unroll
      for (int mf = 0; mf < 4; ++mf) {
        const int m = wm + (mf << 4) + c;
        af[mf] = *(const bf16x8*)&As[((m << 6) + (kc << 5) + (g << 3)) ^ ((m & 7) << 3)];
      }
#pragma unroll
      for (int nf = 0; nf < 4; ++nf) {
        const int n = wn + (nf << 4) + c;
        bfr[nf] = *(const bf16x8*)&Bs[((n << 6) + (kc << 5) + (g << 3)) ^ ((n & 7) << 3)];
      }
#pragma unroll
      for (int mf = 0; mf < 4; ++mf)
#pragma unroll
        for (int nf = 0; nf < 4; ++nf)
          acc[mf][nf] = __builtin_amdgcn_mfma_f32_16x16x32_bf16(af[mf], bfr[nf], acc[mf][nf], 0, 0, 0);
    }
  }
#pragma unroll
  for (int nf = 0; nf < 4; ++nf) {
    const int n = n0 + wn + (nf << 4) + c;
    const float bb = bias[n];
#pragma unroll
    for (int mf = 0; mf < 4; ++mf) {
      const int mrow = m0 + wm + (mf << 4) + (g << 2);
#pragma unroll
      for (int r = 0; r < 4; ++r) {
        const float val = acc[mf][nf][r] + bb;
        if (BF16OUT)
          ((unsigned short*)Y)[((size_t)(mrow + r) << 10) + n] = f2b(val);
        else
          ((float*)Y)[((size_t)(mrow + r) << 10) + n] = val;
      }
    }
  }
}

// ---------- bf16 transpose: Vb [b][t][d] -> Vt [b][d][t] ----------
__global__ __launch_bounds__(256) void transpose_bf16(const unsigned short* __restrict__ Vb,
                                                      unsigned short* __restrict__ Vt) {
  __shared__ unsigned short tile[64][73];
  const int b = blockIdx.z;
  const int t0 = blockIdx.x << 6, d0 = blockIdx.y << 6;
  const int row = threadIdx.x >> 2, cq = (threadIdx.x & 3) << 4;
  const unsigned short* src = &Vb[((size_t)((b << 11) + t0 + row) << 10) + d0 + cq];
  const uint4 va = *(const uint4*)&src[0];
  const uint4 vb2 = *(const uint4*)&src[8];
  const unsigned in[8] = {va.x, va.y, va.z, va.w, vb2.x, vb2.y, vb2.z, vb2.w};
#pragma unroll
  for (int e = 0; e < 8; ++e) {
    tile[row][cq + 2 * e] = (unsigned short)in[e];
    tile[row][cq + 2 * e + 1] = (unsigned short)(in[e] >> 16);
  }
  __syncthreads();
  unsigned o[8];
#pragma unroll
  for (int e = 0; e < 8; ++e)
    o[e] = (unsigned)tile[cq + 2 * e][row] | ((unsigned)tile[cq + 2 * e + 1][row] << 16);
  unsigned short* dst = &Vt[((size_t)((b << 10) + d0 + row) << 11) + t0 + cq];
  uint4 lo, hi;
  lo.x = o[0]; lo.y = o[1]; lo.z = o[2]; lo.w = o[3];
  hi.x = o[4]; hi.y = o[5]; hi.z = o[6]; hi.w = o[7];
  *(uint4*)&dst[0] = lo;
  *(uint4*)&dst[8] = hi;
}

// ---------- per-32-row block sums of V ----------
__global__ __launch_bounds__(256) void vblk32(const unsigned short* __restrict__ Vb,
                                              float* __restrict__ Blk) {
  const int b = blockIdx.x >> 6, t = blockIdx.x & 63;
  const int d4 = threadIdx.x << 2;
  float s0 = 0.f, s1 = 0.f, s2 = 0.f, s3 = 0.f;
  for (int j = 0; j < 32; ++j) {
    const uint2 v = *(const uint2*)&Vb[((size_t)((b << 11) + (t << 5) + j) << 10) + d4];
    s0 += blo(v.x); s1 += bhi(v.x); s2 += blo(v.y); s3 += bhi(v.y);
  }
  float4 o = {s0, s1, s2, s3};
  *(float4*)&Blk[((size_t)((b << 6) + t) << 10) + d4] = o;
}

// ---------- suffix over 64 tiles: Suf[b][ts][d] = sum_{t>=ts} Blk; Suf[b][64][d]=0 ----------
__global__ __launch_bounds__(256) void vsuffix32(const float* __restrict__ Blk, float* __restrict__ Suf) {
  const int idx = blockIdx.x * 256 + threadIdx.x;
  const int b = idx >> 10, d = idx & 1023;
  float s = 0.f;
  Suf[((size_t)(b * 65 + 64) << 10) + d] = 0.f;
  for (int t = 63; t >= 0; --t) {
    s += Blk[((size_t)((b << 6) + t) << 10) + d];
    Suf[((size_t)(b * 65 + t) << 10) + d] = s;
  }
}

// ---------- barrier-free MFMA attention, head-axis softmax ----------
// Wave = one unit (b, i-tile16, j-strip, d-half). Swapped QK^T (A=K,B=Q) => lane holds
// all 16 head-scores for i=c, j=4g+r. Softmax lane-local (2-pass over head groups);
// PV A-frags built in-register via ds_bpermute; no LDS, no barriers.
__global__ __launch_bounds__(256, 1) void attn_v3(const unsigned short* __restrict__ Qb,
                                                  const unsigned short* __restrict__ Kb,
                                                  const unsigned short* __restrict__ Vt,
                                                  const float* __restrict__ Suf,
                                                  unsigned short* __restrict__ AO0,
                                                  unsigned short* __restrict__ AO1,
                                                  unsigned short* __restrict__ AO2) {
  const int u = blockIdx.x * 4 + (threadIdx.x >> 6);
  const int l = threadIdx.x & 63, g = l >> 4, c = l & 15;
  const int dh = u & 1;
  const int v = u >> 1;
  const int b = v & 1;
  const int w2 = v >> 1;  // 0..377
  int it, s, nc;
  if (w2 < 372) {
    const int q = (w2 * 21846) >> 16;  // w2/3
    it = 127 - q;
    s = w2 - 3 * q;
    nc = 3;
  } else {
    const int r = w2 - 372;
    if (r < 2) { it = 3; s = r; nc = 2; }
    else if (r < 4) { it = 2; s = r - 2; nc = 2; }
    else if (r == 4) { it = 1; s = 0; nc = 1; }
    else { it = 0; s = 0; nc = 1; }
  }
  const int nt = (it + 2) >> 1;
  const int lo = (s * nt) / nc, hi = ((s + 1) * nt) / nc;
  const int i0 = it << 4;
  const int hs = dh << 3;

  // Q fragments: all 16 heads, full d (B-frag: col i=c, k elems)
  bf16x8 qf[32];
  const unsigned short* qbase = &Qb[((size_t)(((b << 11) + i0 + c)) << 10) + (g << 3)];
#pragma unroll
  for (int h = 0; h < 16; ++h) {
    qf[2 * h] = *(const bf16x8*)&qbase[h << 6];
    qf[2 * h + 1] = *(const bf16x8*)&qbase[(h << 6) + 32];
  }

  f32x4 acc[8][4];
#pragma unroll
  for (int hh = 0; hh < 8; ++hh)
#pragma unroll
    for (int cc = 0; cc < 4; ++cc) acc[hh][cc] = {0.f, 0.f, 0.f, 0.f};

  const int adrA = (((g & 1) << 5) | c) << 2;
  const int adrB = adrA + 64;
  const bool tsel = g >= 2;
  const float SC = 0.04508422f;  // log2(e)/32

  for (int ts = lo; ts < hi; ++ts) {
    const int j0 = ts << 5;
    unsigned Ea[8], Eb[8], Ec[8], Ed[8];
#pragma unroll
    for (int tau = 0; tau < 2; ++tau) {
      const int j16 = j0 + (tau << 4);
      const unsigned short* kbase = &Kb[((size_t)(((b << 11) + j16 + c)) << 10) + (g << 3)];
      f32x4 sum = {0.f, 0.f, 0.f, 0.f};
      // pass 1: other head group (sum only)
      {
        const int h0 = (1 - dh) << 3;
#pragma unroll
        for (int hh = 0; hh < 8; ++hh) {
          const int h = h0 + hh;
          f32x4 a = {0.f, 0.f, 0.f, 0.f};
          a = __builtin_amdgcn_mfma_f32_16x16x32_bf16(*(const bf16x8*)&kbase[h << 6], qf[2 * h], a, 0, 0, 0);
          a = __builtin_amdgcn_mfma_f32_16x16x32_bf16(*(const bf16x8*)&kbase[(h << 6) + 32], qf[2 * h + 1], a, 0, 0, 0);
#pragma unroll
          for (int r = 0; r < 4; ++r) sum[r] += exp2f(a[r] * SC);
        }
      }
      // pass 2: own head group
      f32x4 ex[8];
      {
#pragma unroll
        for (int hh = 0; hh < 8; ++hh) {
          const int h = hs + hh;
          f32x4 a = {0.f, 0.f, 0.f, 0.f};
          a = __builtin_amdgcn_mfma_f32_16x16x32_bf16(*(const bf16x8*)&kbase[h << 6], qf[2 * h], a, 0, 0, 0);
          a = __builtin_amdgcn_mfma_f32_16x16x32_bf16(*(const bf16x8*)&kbase[(h << 6) + 32], qf[2 * h + 1], a, 0, 0, 0);
#pragma unroll
          for (int r = 0; r < 4; ++r) {
            ex[hh][r] = exp2f(a[r] * SC);
            sum[r] += ex[hh][r];
          }
        }
      }
      f32x4 inv;
#pragma unroll
      for (int r = 0; r < 4; ++r) inv[r] = __builtin_amdgcn_rcpf(sum[r]);
#pragma unroll
      for (int hh = 0; hh < 8; ++hh) {
        float wv[4];
#pragma unroll
        for (int r = 0; r < 4; ++r) {
          const bool msk = (j16 + (g << 2) + r) > (i0 + c);
          wv[r] = msk ? 0.0625f : ex[hh][r] * inv[r];
        }
        const unsigned p0 = pack_bf16(wv[0], wv[1]);
        const unsigned p1 = pack_bf16(wv[2], wv[3]);
        if (tau == 0) { Ea[hh] = p0; Eb[hh] = p1; }
        else { Ec[hh] = p0; Ed[hh] = p1; }
      }
    }
    // relayout (8 bperm + 4 cndmask per head) + PV
#pragma unroll
    for (int hh = 0; hh < 8; ++hh) {
      const int h = hs + hh;
      const unsigned a0A = __builtin_amdgcn_ds_bpermute(adrA, (int)Ea[hh]);
      const unsigned a1A = __builtin_amdgcn_ds_bpermute(adrA, (int)Eb[hh]);
      const unsigned c0A = __builtin_amdgcn_ds_bpermute(adrA, (int)Ec[hh]);
      const unsigned c1A = __builtin_amdgcn_ds_bpermute(adrA, (int)Ed[hh]);
      const unsigned a0B = __builtin_amdgcn_ds_bpermute(adrB, (int)Ea[hh]);
      const unsigned a1B = __builtin_amdgcn_ds_bpermute(adrB, (int)Eb[hh]);
      const unsigned c0B = __builtin_amdgcn_ds_bpermute(adrB, (int)Ec[hh]);
      const unsigned c1B = __builtin_amdgcn_ds_bpermute(adrB, (int)Ed[hh]);
      union { bf16x8 v; unsigned u[4]; } pa;
      pa.u[0] = tsel ? c0A : a0A;
      pa.u[1] = tsel ? c1A : a1A;
      pa.u[2] = tsel ? c0B : a0B;
      pa.u[3] = tsel ? c1B : a1B;
      const unsigned short* vbase = &Vt[(((size_t)((b << 10) + (h << 6) + c)) << 11) + j0 + (g << 3)];
#pragma unroll
      for (int cc = 0; cc < 4; ++cc)
        acc[hh][cc] = __builtin_amdgcn_mfma_f32_16x16x32_bf16(pa.v, *(const bf16x8*)&vbase[cc << 15],
                                                              acc[hh][cc], 0, 0, 0);
    }
  }
  // suffix (last strip only) + store bf16 partials
  unsigned short* AOp = s == 0 ? AO0 : s == 1 ? AO1 : AO2;
  const float* sufb = &Suf[((size_t)(b * 65 + nt)) << 10];
  const bool last = (hi == nt);
#pragma unroll
  for (int hh = 0; hh < 8; ++hh) {
#pragma unroll
    for (int cc = 0; cc < 4; ++cc) {
      const int d = ((hs + hh) << 6) + (cc << 4) + c;
      const float sa = last ? 0.0625f * sufb[d] : 0.0f;
#pragma unroll
      for (int r = 0; r < 4; ++r)
        AOp[((size_t)((b << 11) + i0 + (g << 2) + r) << 10) + d] = f2b(acc[hh][cc][r] + sa);
    }
  }
}

// ---------- reduce partials (bf16 x nc) -> bf16 A for output GEMM ----------
__global__ __launch_bounds__(256) void aored(const unsigned short* __restrict__ AO0,
                                             const unsigned short* __restrict__ AO1,
                                             const unsigned short* __restrict__ AO2,
                                             unsigned short* __restrict__ AOb) {
  const int i = (blockIdx.x * 256 + threadIdx.x) * 8;
  const int m = i >> 10;
  const int it = (m & 2047) >> 4;
  const int nt = (it + 2) >> 1;
  const int nc = nt < 3 ? nt : 3;
  const uint4 v0 = *(const uint4*)&AO0[i];
  float s[8] = {blo(v0.x), bhi(v0.x), blo(v0.y), bhi(v0.y), blo(v0.z), bhi(v0.z), blo(v0.w), bhi(v0.w)};
  if (nc > 1) {
    const uint4 v1 = *(const uint4*)&AO1[i];
    s[0] += blo(v1.x); s[1] += bhi(v1.x); s[2] += blo(v1.y); s[3] += bhi(v1.y);
    s[4] += blo(v1.z); s[5] += bhi(v1.z); s[6] += blo(v1.w); s[7] += bhi(v1.w);
  }
  if (nc > 2) {
    const uint4 v2 = *(const uint4*)&AO2[i];
    s[0] += blo(v2.x); s[1] += bhi(v2.x); s[2] += blo(v2.y); s[3] += bhi(v2.y);
    s[4] += blo(v2.z); s[5] += bhi(v2.z); s[6] += blo(v2.w); s[7] += bhi(v2.w);
  }
  uint4 o;
  o.x = pack_bf16(s[0], s[1]);
  o.y = pack_bf16(s[2], s[3]);
  o.z = pack_bf16(s[4], s[5]);
  o.w = pack_bf16(s[6], s[7]);
  *(uint4*)&AOb[i] = o;
}

extern "C" void kernel_launch(void* const* d_in, const int* in_sizes, int n_in,
                              void* d_out, int out_size, void* d_ws, size_t ws_size,
                              hipStream_t stream) {
  (void)in_sizes; (void)n_in; (void)out_size; (void)ws_size;
  const float* x = (const float*)d_in[0];
  const float* Wq = (const float*)d_in[1];
  const float* bq = (const float*)d_in[2];
  const float* Wk = (const float*)d_in[3];
  const float* bk = (const float*)d_in[4];
  const float* Wv = (const float*)d_in[5];
  const float* bv = (const float*)d_in[6];
  const float* Wo = (const float*)d_in[7];
  const float* bo = (const float*)d_in[8];
  float* out = (float*)d_out;
  char* ws = (char*)d_ws;

  const size_t MB = 1024 * 1024;
  unsigned short* xb  = (unsigned short*)(ws);            // 8MB; AOb aliases after attn
  unsigned short* Qb  = (unsigned short*)(ws + 8 * MB);   // 8MB
  unsigned short* Kb  = (unsigned short*)(ws + 16 * MB);  // 8MB
  unsigned short* Vb  = (unsigned short*)(ws + 24 * MB);  // 8MB; AO0 aliases after vblk
  unsigned short* Vt  = (unsigned short*)(ws + 32 * MB);  // 8MB
  unsigned short* Wqt = (unsigned short*)(ws + 40 * MB);  // 2MB; Blk/Suf overlay after proj
  unsigned short* Wkt = (unsigned short*)(ws + 42 * MB);
  unsigned short* Wvt = (unsigned short*)(ws + 44 * MB);
  unsigned short* Wot = (unsigned short*)(ws + 46 * MB);
  unsigned short* AO1 = (unsigned short*)(ws + 48 * MB);  // 8MB
  unsigned short* AO2 = (unsigned short*)(ws + 56 * MB);  // 8MB -> 64MB total
  float* Blk = (float*)(ws + 40 * MB);                    // 512KB (over Wqt)
  float* Suf = (float*)(ws + 40 * MB + 512 * 1024);       // 520KB
  unsigned short* AO0 = Vb;
  unsigned short* AOb = xb;

  hipLaunchKernelGGL(wtrans, dim3(16, 16, 4), dim3(256), 0, stream,
                     Wq, Wk, Wv, Wo, Wqt, Wkt, Wvt, Wot);
  hipLaunchKernelGGL(xconv, dim3(2048), dim3(256), 0, stream, x, xb);
  hipLaunchKernelGGL((gemm_mfma<true>), dim3(8, 32, 3), dim3(256), 0, stream,
                     xb, Wqt, Wkt, Wvt, bq, bk, bv, (void*)Qb, (void*)Kb, (void*)Vb);
  hipLaunchKernelGGL(transpose_bf16, dim3(32, 16, 2), dim3(256), 0, stream, Vb, Vt);
  hipLaunchKernelGGL(vblk32, dim3(128), dim3(256), 0, stream, Vb, Blk);
  hipLaunchKernelGGL(vsuffix32, dim3(8), dim3(256), 0, stream, Blk, Suf);
  hipLaunchKernelGGL(attn_v3, dim3(378), dim3(256), 0, stream, Qb, Kb, Vt, Suf, AO0, AO1, AO2);
  hipLaunchKernelGGL(aored, dim3(2048), dim3(256), 0, stream, AO0, AO1, AO2, AOb);
  hipLaunchKernelGGL((gemm_mfma<false>), dim3(8, 32, 1), dim3(256), 0, stream,
                     AOb, Wot, Wot, Wot, bo, bo, bo, (void*)out, (void*)out, (void*)out);
}

// Round 4
// 549.501 us; speedup vs baseline: 6.2583x; 1.1800x over previous
//
#include <hip/hip_runtime.h>
#include <hip/hip_bf16.h>

#define B_ 2
#define T_ 2048
#define D_ 1024
#define H_ 16
#define TPC 4

typedef __attribute__((ext_vector_type(8))) short bf16x8;
typedef __attribute__((ext_vector_type(4))) float f32x4;

__device__ __forceinline__ unsigned pack_bf16(float x, float y) {
  unsigned xb = __float_as_uint(x), yb = __float_as_uint(y);
  xb += 0x7fffu + ((xb >> 16) & 1u);
  yb += 0x7fffu + ((yb >> 16) & 1u);
  return (xb >> 16) | (yb & 0xffff0000u);
}
__device__ __forceinline__ unsigned short f2b(float x) {
  unsigned u = __float_as_uint(x);
  u += 0x7fffu + ((u >> 16) & 1u);
  return (unsigned short)(u >> 16);
}
__device__ __forceinline__ float blo(unsigned u) { return __uint_as_float(u << 16); }
__device__ __forceinline__ float bhi(unsigned u) { return __uint_as_float(u & 0xffff0000u); }

__device__ __forceinline__ void gld_lds16(const unsigned short* g, unsigned short* l) {
  __builtin_amdgcn_global_load_lds(
      (const __attribute__((address_space(1))) unsigned int*)g,
      (__attribute__((address_space(3))) unsigned int*)l, 16, 0, 0);
}

// ---------- weight transpose + convert: Wt[n][k] = bf16(W[k][n]), 4 weights ----------
__global__ __launch_bounds__(256) void wtrans(const float* __restrict__ W0, const float* __restrict__ W1,
                                              const float* __restrict__ W2, const float* __restrict__ W3,
                                              unsigned short* __restrict__ T0, unsigned short* __restrict__ T1,
                                              unsigned short* __restrict__ T2, unsigned short* __restrict__ T3) {
  const int z = blockIdx.z;
  const float* W = z == 0 ? W0 : z == 1 ? W1 : z == 2 ? W2 : W3;
  unsigned short* T = z == 0 ? T0 : z == 1 ? T1 : z == 2 ? T2 : T3;
  __shared__ unsigned short t[64][72];
  const int k0 = blockIdx.x << 6, n0 = blockIdx.y << 6;
  const int r = threadIdx.x >> 2, c16 = (threadIdx.x & 3) << 4;
#pragma unroll
  for (int e = 0; e < 4; ++e) {
    const float4 v = *(const float4*)&W[(size_t)(k0 + r) * 1024 + n0 + c16 + e * 4];
    t[r][c16 + e * 4 + 0] = f2b(v.x);
    t[r][c16 + e * 4 + 1] = f2b(v.y);
    t[r][c16 + e * 4 + 2] = f2b(v.z);
    t[r][c16 + e * 4 + 3] = f2b(v.w);
  }
  __syncthreads();
  unsigned short o[16];
#pragma unroll
  for (int e = 0; e < 16; ++e) o[e] = t[c16 + e][r];
  unsigned short* dst = &T[(size_t)(n0 + r) * 1024 + k0 + c16];
  *(uint4*)&dst[0] = *(uint4*)&o[0];
  *(uint4*)&dst[8] = *(uint4*)&o[8];
}

// ---------- x fp32 -> bf16 ----------
__global__ __launch_bounds__(256) void xconv(const float* __restrict__ x, unsigned short* __restrict__ xb) {
  const int i = (blockIdx.x * 256 + threadIdx.x) * 8;
  const float4 a = *(const float4*)&x[i];
  const float4 b = *(const float4*)&x[i + 4];
  uint4 o;
  o.x = pack_bf16(a.x, a.y);
  o.y = pack_bf16(a.z, a.w);
  o.z = pack_bf16(b.x, b.y);
  o.w = pack_bf16(b.z, b.w);
  *(uint4*)&xb[i] = o;
}

// ---------- bf16 MFMA GEMM: Y = A[M,1024] @ Bt[n][k]^T + bias ----------
template <bool BF16OUT>
__global__ __launch_bounds__(256) void gemm_mfma(const unsigned short* __restrict__ A,
                                                 const unsigned short* __restrict__ B0,
                                                 const unsigned short* __restrict__ B1,
                                                 const unsigned short* __restrict__ B2,
                                                 const float* __restrict__ bi0, const float* __restrict__ bi1,
                                                 const float* __restrict__ bi2,
                                                 void* __restrict__ Y0, void* __restrict__ Y1,
                                                 void* __restrict__ Y2) {
  const int z = blockIdx.z;
  const unsigned short* Bt = z == 0 ? B0 : z == 1 ? B1 : B2;
  const float* bias = z == 0 ? bi0 : z == 1 ? bi1 : bi2;
  void* Y = z == 0 ? Y0 : z == 1 ? Y1 : Y2;
  __shared__ unsigned short As[8192];
  __shared__ unsigned short Bs[8192];
  const int tid = threadIdx.x;
  const int m0 = blockIdx.y << 7, n0 = blockIdx.x << 7;
  const int w = tid >> 6, l = tid & 63, g = l >> 4, c = l & 15;
  const int wm = (w >> 1) << 6, wn = (w & 1) << 6;
  const int srow = tid >> 3;
  const int skel = ((tid & 7) ^ (srow & 7)) << 3;
  const unsigned short* ga = &A[(size_t)(m0 + srow) * 1024 + skel];
  const unsigned short* gb = &Bt[(size_t)(n0 + srow) * 1024 + skel];
  unsigned short* la = &As[tid << 3];
  unsigned short* lb = &Bs[tid << 3];
  f32x4 acc[4][4];
#pragma unroll
  for (int i = 0; i < 4; ++i)
#pragma unroll
    for (int j = 0; j < 4; ++j) acc[i][j] = {0.f, 0.f, 0.f, 0.f};
  for (int k0 = 0; k0 < 1024; k0 += 64) {
    __syncthreads();
#pragma unroll
    for (int a = 0; a < 4; ++a) {
      gld_lds16(ga + (size_t)(a << 5) * 1024 + k0, la + (a << 11));
      gld_lds16(gb + (size_t)(a << 5) * 1024 + k0, lb + (a << 11));
    }
    __syncthreads();
#pragma unroll
    for (int kc = 0; kc < 2; ++kc) {
      bf16x8 af[4], bfr[4];
#pragma unroll
      for (int mf = 0; mf < 4; ++mf) {
        const int m = wm + (mf << 4) + c;
        af[mf] = *(const bf16x8*)&As[((m << 6) + (kc << 5) + (g << 3)) ^ ((m & 7) << 3)];
      }
#pragma unroll
      for (int nf = 0; nf < 4; ++nf) {
        const int n = wn + (nf << 4) + c;
        bfr[nf] = *(const bf16x8*)&Bs[((n << 6) + (kc << 5) + (g << 3)) ^ ((n & 7) << 3)];
      }
#pragma unroll
      for (int mf = 0; mf < 4; ++mf)
#pragma unroll
        for (int nf = 0; nf < 4; ++nf)
          acc[mf][nf] = __builtin_amdgcn_mfma_f32_16x16x32_bf16(af[mf], bfr[nf], acc[mf][nf], 0, 0, 0);
    }
  }
#pragma unroll
  for (int nf = 0; nf < 4; ++nf) {
    const int n = n0 + wn + (nf << 4) + c;
    const float bb = bias[n];
#pragma unroll
    for (int mf = 0; mf < 4; ++mf) {
      const int mrow = m0 + wm + (mf << 4) + (g << 2);
#pragma unroll
      for (int r = 0; r < 4; ++r) {
        const float val = acc[mf][nf][r] + bb;
        if (BF16OUT)
          ((unsigned short*)Y)[((size_t)(mrow + r) << 10) + n] = f2b(val);
        else
          ((float*)Y)[((size_t)(mrow + r) << 10) + n] = val;
      }
    }
  }
}

// ---------- bf16 transpose: Vb [b][t][d] -> Vt [b][d][t] ----------
__global__ __launch_bounds__(256) void transpose_bf16(const unsigned short* __restrict__ Vb,
                                                      unsigned short* __restrict__ Vt) {
  __shared__ unsigned short tile[64][73];
  const int b = blockIdx.z;
  const int t0 = blockIdx.x << 6, d0 = blockIdx.y << 6;
  const int row = threadIdx.x >> 2, cq = (threadIdx.x & 3) << 4;
  const unsigned short* src = &Vb[((size_t)((b << 11) + t0 + row) << 10) + d0 + cq];
  const uint4 va = *(const uint4*)&src[0];
  const uint4 vb2 = *(const uint4*)&src[8];
  const unsigned in[8] = {va.x, va.y, va.z, va.w, vb2.x, vb2.y, vb2.z, vb2.w};
#pragma unroll
  for (int e = 0; e < 8; ++e) {
    tile[row][cq + 2 * e] = (unsigned short)in[e];
    tile[row][cq + 2 * e + 1] = (unsigned short)(in[e] >> 16);
  }
  __syncthreads();
  unsigned o[8];
#pragma unroll
  for (int e = 0; e < 8; ++e)
    o[e] = (unsigned)tile[cq + 2 * e][row] | ((unsigned)tile[cq + 2 * e + 1][row] << 16);
  unsigned short* dst = &Vt[((size_t)((b << 10) + d0 + row) << 11) + t0 + cq];
  uint4 lo, hi;
  lo.x = o[0]; lo.y = o[1]; lo.z = o[2]; lo.w = o[3];
  hi.x = o[4]; hi.y = o[5]; hi.z = o[6]; hi.w = o[7];
  *(uint4*)&dst[0] = lo;
  *(uint4*)&dst[8] = hi;
}

// ---------- per-32-row block sums of V ----------
__global__ __launch_bounds__(256) void vblk32(const unsigned short* __restrict__ Vb,
                                              float* __restrict__ Blk) {
  const int b = blockIdx.x >> 6, t = blockIdx.x & 63;
  const int d4 = threadIdx.x << 2;
  float s0 = 0.f, s1 = 0.f, s2 = 0.f, s3 = 0.f;
  for (int j = 0; j < 32; ++j) {
    const uint2 v = *(const uint2*)&Vb[((size_t)((b << 11) + (t << 5) + j) << 10) + d4];
    s0 += blo(v.x); s1 += bhi(v.x); s2 += blo(v.y); s3 += bhi(v.y);
  }
  float4 o = {s0, s1, s2, s3};
  *(float4*)&Blk[((size_t)((b << 6) + t) << 10) + d4] = o;
}

// ---------- suffix over 64 tiles ----------
__global__ __launch_bounds__(256) void vsuffix32(const float* __restrict__ Blk, float* __restrict__ Suf) {
  const int idx = blockIdx.x * 256 + threadIdx.x;
  const int b = idx >> 10, d = idx & 1023;
  float s = 0.f;
  Suf[((size_t)(b * 65 + 64) << 10) + d] = 0.f;
  for (int t = 63; t >= 0; --t) {
    s += Blk[((size_t)((b << 6) + t) << 10) + d];
    Suf[((size_t)(b * 65 + t) << 10) + d] = s;
  }
}

// ---------- LDS-staged MFMA attention, head-axis softmax ----------
// Block = 8 waves, i-tile 64 (wave = (iw: 16 rows, dh: 8 heads)). Per 32-j tile:
// cooperative K/V staging (swizzled), per-wave QK^T on own 8 heads, Sigma-exp exchange
// with dh-partner via LDS (softmax couples heads only through the denominator),
// bpermute weight relayout (v3-verified), PV MFMA. Output: atomicAdd into fp32 AO.
// Masked-beyond-tiles handled analytically via suffix sums in aocvt.
__global__ __launch_bounds__(512, 2) void attn_v4(const unsigned short* __restrict__ Qb,
                                                  const unsigned short* __restrict__ Kb,
                                                  const unsigned short* __restrict__ Vt,
                                                  float* __restrict__ AO) {
  __shared__ unsigned short Ks[32 * 1024];  // 64 KB, chunk-XOR swizzled
  __shared__ unsigned short Vs[1024 * 32];  // 64 KB, jc^(d&3) swizzled
  __shared__ float Sx[4096];                // 16 KB partial-sum exchange

  const int s = blockIdx.x;
  const int it = 31 - blockIdx.y;  // heavy-first
  const int b = blockIdx.z;
  const int nt = 2 * it + 2;
  const int nc = (nt + TPC - 1) / TPC;
  if (s >= nc) return;
  const int i0 = it << 6;
  const int tid = threadIdx.x;
  const int w = tid >> 6, l = tid & 63, g = l >> 4, c = l & 15;
  const int iw = w >> 1, dh = w & 1;
  const int i0w = i0 + (iw << 4);
  const int hs = dh << 3;
  const int ib = i0w + c;

  // own-head Q B-frags (64 VGPR)
  bf16x8 qf[16];
  const unsigned short* qbase = &Qb[((size_t)((b << 11) + i0w + c) << 10) + (g << 3)];
#pragma unroll
  for (int hh = 0; hh < 8; ++hh) {
    qf[2 * hh] = *(const bf16x8*)&qbase[(hs + hh) << 6];
    qf[2 * hh + 1] = *(const bf16x8*)&qbase[((hs + hh) << 6) + 32];
  }

  f32x4 acc[8][4];
#pragma unroll
  for (int hh = 0; hh < 8; ++hh)
#pragma unroll
    for (int cc = 0; cc < 4; ++cc) acc[hh][cc] = {0.f, 0.f, 0.f, 0.f};

  const float SC = 0.04508422f;  // log2(e)/32
  const int adrA = (((g & 1) << 5) | c) << 2;
  const int adrB = adrA + 64;
  const bool tsel = g >= 2;

  for (int ts = s; ts < nt; ts += nc) {
    const int j0 = ts << 5;
    __syncthreads();  // prior tile's LDS reads complete
    // stage K (4096 chunks) and V (4096 chunks)
#pragma unroll
    for (int kk = 0; kk < 8; ++kk) {
      const int q = tid + (kk << 9);
      const int row = q >> 7, cc8 = q & 127;
      const int scc = cc8 ^ (row & 7);
      gld_lds16(&Kb[((size_t)((b << 11) + j0 + row) << 10) + (scc << 3)], &Ks[q << 3]);
    }
#pragma unroll
    for (int kk = 0; kk < 8; ++kk) {
      const int q = tid + (kk << 9);
      const int d = q >> 2, jc = q & 3;
      const int jcg = jc ^ (d & 3);
      gld_lds16(&Vt[(((size_t)((b << 10) + d)) << 11) + j0 + (jcg << 3)], &Vs[q << 3]);
    }
    __syncthreads();  // staging complete (vmcnt drained by barrier)

    const bool live = (j0 <= i0w + 15);
    unsigned Ea[8], Eb[8], Ec[8], Ed[8];
    f32x4 psum0 = {0.f, 0.f, 0.f, 0.f}, psum1 = {0.f, 0.f, 0.f, 0.f};
    if (live) {
#pragma unroll
      for (int tau = 0; tau < 2; ++tau) {
        const int krow = (tau << 4) + c;
        const int kx = krow & 7;
        f32x4 ps = {0.f, 0.f, 0.f, 0.f};
#pragma unroll
        for (int hh = 0; hh < 8; ++hh) {
          const int e8 = (hs + hh) << 3;
          const bf16x8 k0 = *(const bf16x8*)&Ks[((krow << 7) + ((e8 + g) ^ kx)) << 3];
          const bf16x8 k1 = *(const bf16x8*)&Ks[((krow << 7) + ((e8 + 4 + g) ^ kx)) << 3];
          f32x4 a = {0.f, 0.f, 0.f, 0.f};
          a = __builtin_amdgcn_mfma_f32_16x16x32_bf16(k0, qf[2 * hh], a, 0, 0, 0);
          a = __builtin_amdgcn_mfma_f32_16x16x32_bf16(k1, qf[2 * hh + 1], a, 0, 0, 0);
          const float e0 = exp2f(a[0] * SC), e1 = exp2f(a[1] * SC);
          const float e2 = exp2f(a[2] * SC), e3 = exp2f(a[3] * SC);
          ps[0] += e0; ps[1] += e1; ps[2] += e2; ps[3] += e3;
          const unsigned p0 = pack_bf16(e0, e1), p1 = pack_bf16(e2, e3);
          if (tau == 0) { Ea[hh] = p0; Eb[hh] = p1; }
          else { Ec[hh] = p0; Ed[hh] = p1; }
        }
        if (tau == 0) psum0 = ps; else psum1 = ps;
      }
      const int sxb = ((iw << 1) + dh) << 9;
      *(f32x4*)&Sx[sxb + (l << 2)] = psum0;
      *(f32x4*)&Sx[sxb + 256 + (l << 2)] = psum1;
    }
    __syncthreads();  // Sx ready
    if (live) {
      const int sxp = ((iw << 1) + (1 - dh)) << 9;
      const f32x4 q0 = *(const f32x4*)&Sx[sxp + (l << 2)];
      const f32x4 q1 = *(const f32x4*)&Sx[sxp + 256 + (l << 2)];
      f32x4 inv0, inv1;
#pragma unroll
      for (int r = 0; r < 4; ++r) {
        inv0[r] = __builtin_amdgcn_rcpf(psum0[r] + q0[r]);
        inv1[r] = __builtin_amdgcn_rcpf(psum1[r] + q1[r]);
      }
      const int jb = j0 + (g << 2);
      const bool ma0 = jb + 0 > ib, ma1 = jb + 1 > ib, ma2 = jb + 2 > ib, ma3 = jb + 3 > ib;
      const bool mb0 = jb + 16 > ib, mb1 = jb + 17 > ib, mb2 = jb + 18 > ib, mb3 = jb + 19 > ib;
#pragma unroll
      for (int hh = 0; hh < 8; ++hh) {
        const float wa0 = ma0 ? 0.0625f : blo(Ea[hh]) * inv0[0];
        const float wa1 = ma1 ? 0.0625f : bhi(Ea[hh]) * inv0[1];
        const float wa2 = ma2 ? 0.0625f : blo(Eb[hh]) * inv0[2];
        const float wa3 = ma3 ? 0.0625f : bhi(Eb[hh]) * inv0[3];
        const float wc0 = mb0 ? 0.0625f : blo(Ec[hh]) * inv1[0];
        const float wc1 = mb1 ? 0.0625f : bhi(Ec[hh]) * inv1[1];
        const float wc2 = mb2 ? 0.0625f : blo(Ed[hh]) * inv1[2];
        const float wc3 = mb3 ? 0.0625f : bhi(Ed[hh]) * inv1[3];
        Ea[hh] = pack_bf16(wa0, wa1);
        Eb[hh] = pack_bf16(wa2, wa3);
        Ec[hh] = pack_bf16(wc0, wc1);
        Ed[hh] = pack_bf16(wc2, wc3);
      }
    } else {
#pragma unroll
      for (int hh = 0; hh < 8; ++hh) {
        Ea[hh] = 0x3D803D80u; Eb[hh] = 0x3D803D80u;
        Ec[hh] = 0x3D803D80u; Ed[hh] = 0x3D803D80u;
      }
    }
    // bpermute relayout + PV (V from LDS)
#pragma unroll
    for (int hh = 0; hh < 8; ++hh) {
      const int h = hs + hh;
      const unsigned a0A = __builtin_amdgcn_ds_bpermute(adrA, (int)Ea[hh]);
      const unsigned a1A = __builtin_amdgcn_ds_bpermute(adrA, (int)Eb[hh]);
      const unsigned c0A = __builtin_amdgcn_ds_bpermute(adrA, (int)Ec[hh]);
      const unsigned c1A = __builtin_amdgcn_ds_bpermute(adrA, (int)Ed[hh]);
      const unsigned a0B = __builtin_amdgcn_ds_bpermute(adrB, (int)Ea[hh]);
      const unsigned a1B = __builtin_amdgcn_ds_bpermute(adrB, (int)Eb[hh]);
      const unsigned c0B = __builtin_amdgcn_ds_bpermute(adrB, (int)Ec[hh]);
      const unsigned c1B = __builtin_amdgcn_ds_bpermute(adrB, (int)Ed[hh]);
      union { bf16x8 v; unsigned u[4]; } pa;
      pa.u[0] = tsel ? c0A : a0A;
      pa.u[1] = tsel ? c1A : a1A;
      pa.u[2] = tsel ? c0B : a0B;
      pa.u[3] = tsel ? c1B : a1B;
#pragma unroll
      for (int cc = 0; cc < 4; ++cc) {
        const int d = (h << 6) + (cc << 4) + c;
        const bf16x8 bv = *(const bf16x8*)&Vs[(((d << 2) + (g ^ (d & 3))) << 3)];
        acc[hh][cc] = __builtin_amdgcn_mfma_f32_16x16x32_bf16(pa.v, bv, acc[hh][cc], 0, 0, 0);
      }
    }
  }
  // epilogue: atomic accumulate into fp32 AO
#pragma unroll
  for (int hh = 0; hh < 8; ++hh)
#pragma unroll
    for (int cc = 0; cc < 4; ++cc)
#pragma unroll
      for (int r = 0; r < 4; ++r)
        atomicAdd(&AO[((size_t)((b << 11) + i0w + (g << 2) + r) << 10) + ((hs + hh) << 6) + (cc << 4) + c],
                  acc[hh][cc][r]);
}

// ---------- AO fp32 + (1/16)*suffix -> bf16 ----------
__global__ __launch_bounds__(256) void aocvt(const float* __restrict__ AO, const float* __restrict__ Suf,
                                             unsigned short* __restrict__ AOb) {
  const int i = (blockIdx.x * 256 + threadIdx.x) << 3;
  const int m = i >> 10;
  const int b = m >> 11, it = (m & 2047) >> 6;
  const int d0 = i & 1023;
  const float* sp = &Suf[((size_t)(b * 65 + 2 * it + 2) << 10) + d0];
  const float4 a0 = *(const float4*)&AO[i];
  const float4 a1 = *(const float4*)&AO[i + 4];
  const float4 s0 = *(const float4*)&sp[0];
  const float4 s1 = *(const float4*)&sp[4];
  uint4 o;
  o.x = pack_bf16(a0.x + 0.0625f * s0.x, a0.y + 0.0625f * s0.y);
  o.y = pack_bf16(a0.z + 0.0625f * s0.z, a0.w + 0.0625f * s0.w);
  o.z = pack_bf16(a1.x + 0.0625f * s1.x, a1.y + 0.0625f * s1.y);
  o.w = pack_bf16(a1.z + 0.0625f * s1.z, a1.w + 0.0625f * s1.w);
  *(uint4*)&AOb[i] = o;
}

extern "C" void kernel_launch(void* const* d_in, const int* in_sizes, int n_in,
                              void* d_out, int out_size, void* d_ws, size_t ws_size,
                              hipStream_t stream) {
  (void)in_sizes; (void)n_in; (void)out_size; (void)ws_size;
  const float* x = (const float*)d_in[0];
  const float* Wq = (const float*)d_in[1];
  const float* bq = (const float*)d_in[2];
  const float* Wk = (const float*)d_in[3];
  const float* bk = (const float*)d_in[4];
  const float* Wv = (const float*)d_in[5];
  const float* bv = (const float*)d_in[6];
  const float* Wo = (const float*)d_in[7];
  const float* bo = (const float*)d_in[8];
  float* out = (float*)d_out;
  char* ws = (char*)d_ws;

  const size_t MB = 1024 * 1024;
  unsigned short* xb  = (unsigned short*)(ws);            // 8MB; AOb aliases after projections
  unsigned short* Qb  = (unsigned short*)(ws + 8 * MB);   // 8MB
  unsigned short* Kb  = (unsigned short*)(ws + 16 * MB);  // 8MB
  unsigned short* Vb  = (unsigned short*)(ws + 24 * MB);  // 8MB
  unsigned short* Vt  = (unsigned short*)(ws + 32 * MB);  // 8MB
  unsigned short* Wqt = (unsigned short*)(ws + 40 * MB);  // 2MB each; Blk/Suf overlay Wqt/Wkt after proj
  unsigned short* Wkt = (unsigned short*)(ws + 42 * MB);
  unsigned short* Wvt = (unsigned short*)(ws + 44 * MB);
  unsigned short* Wot = (unsigned short*)(ws + 46 * MB);
  float* AO = (float*)(ws + 48 * MB);                     // 16MB fp32 accumulation
  float* Blk = (float*)(ws + 40 * MB);                    // 512KB (over Wqt)
  float* Suf = (float*)(ws + 40 * MB + 512 * 1024);       // 520KB (over Wqt/Wkt)
  unsigned short* AOb = xb;

  hipLaunchKernelGGL(wtrans, dim3(16, 16, 4), dim3(256), 0, stream,
                     Wq, Wk, Wv, Wo, Wqt, Wkt, Wvt, Wot);
  hipLaunchKernelGGL(xconv, dim3(2048), dim3(256), 0, stream, x, xb);
  hipLaunchKernelGGL((gemm_mfma<true>), dim3(8, 32, 3), dim3(256), 0, stream,
                     xb, Wqt, Wkt, Wvt, bq, bk, bv, (void*)Qb, (void*)Kb, (void*)Vb);
  hipLaunchKernelGGL(transpose_bf16, dim3(32, 16, 2), dim3(256), 0, stream, Vb, Vt);
  hipLaunchKernelGGL(vblk32, dim3(128), dim3(256), 0, stream, Vb, Blk);
  hipLaunchKernelGGL(vsuffix32, dim3(8), dim3(256), 0, stream, Blk, Suf);
  hipMemsetAsync(AO, 0, (size_t)B_ * T_ * D_ * sizeof(float), stream);
  hipLaunchKernelGGL(attn_v4, dim3(16, 32, 2), dim3(512), 0, stream, Qb, Kb, Vt, AO);
  hipLaunchKernelGGL(aocvt, dim3(2048), dim3(256), 0, stream, AO, Suf, AOb);
  hipLaunchKernelGGL((gemm_mfma<false>), dim3(8, 32, 1), dim3(256), 0, stream,
                     AOb, Wot, Wot, Wot, bo, bo, bo, (void*)out, (void*)out, (void*)out);
}

// Round 5
// 531.057 us; speedup vs baseline: 6.4756x; 1.0347x over previous
//
#include <hip/hip_runtime.h>
#include <hip/hip_bf16.h>

#define B_ 2
#define T_ 2048
#define D_ 1024
#define H_ 16
#define TPC 4

typedef __attribute__((ext_vector_type(8))) short bf16x8;
typedef __attribute__((ext_vector_type(4))) float f32x4;

__device__ __forceinline__ unsigned pack_bf16(float x, float y) {
  unsigned xb = __float_as_uint(x), yb = __float_as_uint(y);
  xb += 0x7fffu + ((xb >> 16) & 1u);
  yb += 0x7fffu + ((yb >> 16) & 1u);
  return (xb >> 16) | (yb & 0xffff0000u);
}
__device__ __forceinline__ unsigned short f2b(float x) {
  unsigned u = __float_as_uint(x);
  u += 0x7fffu + ((u >> 16) & 1u);
  return (unsigned short)(u >> 16);
}
__device__ __forceinline__ float blo(unsigned u) { return __uint_as_float(u << 16); }
__device__ __forceinline__ float bhi(unsigned u) { return __uint_as_float(u & 0xffff0000u); }

__device__ __forceinline__ void gld_lds16(const unsigned short* g, unsigned short* l) {
  __builtin_amdgcn_global_load_lds(
      (const __attribute__((address_space(1))) unsigned int*)g,
      (__attribute__((address_space(3))) unsigned int*)l, 16, 0, 0);
}

// ---------- weight transpose + convert: Wt[n][k] = bf16(W[k][n]), 4 weights ----------
__global__ __launch_bounds__(256) void wtrans(const float* __restrict__ W0, const float* __restrict__ W1,
                                              const float* __restrict__ W2, const float* __restrict__ W3,
                                              unsigned short* __restrict__ T0, unsigned short* __restrict__ T1,
                                              unsigned short* __restrict__ T2, unsigned short* __restrict__ T3) {
  const int z = blockIdx.z;
  const float* W = z == 0 ? W0 : z == 1 ? W1 : z == 2 ? W2 : W3;
  unsigned short* T = z == 0 ? T0 : z == 1 ? T1 : z == 2 ? T2 : T3;
  __shared__ unsigned short t[64][72];
  const int k0 = blockIdx.x << 6, n0 = blockIdx.y << 6;
  const int r = threadIdx.x >> 2, c16 = (threadIdx.x & 3) << 4;
#pragma unroll
  for (int e = 0; e < 4; ++e) {
    const float4 v = *(const float4*)&W[(size_t)(k0 + r) * 1024 + n0 + c16 + e * 4];
    t[r][c16 + e * 4 + 0] = f2b(v.x);
    t[r][c16 + e * 4 + 1] = f2b(v.y);
    t[r][c16 + e * 4 + 2] = f2b(v.z);
    t[r][c16 + e * 4 + 3] = f2b(v.w);
  }
  __syncthreads();
  unsigned short o[16];
#pragma unroll
  for (int e = 0; e < 16; ++e) o[e] = t[c16 + e][r];
  unsigned short* dst = &T[(size_t)(n0 + r) * 1024 + k0 + c16];
  *(uint4*)&dst[0] = *(uint4*)&o[0];
  *(uint4*)&dst[8] = *(uint4*)&o[8];
}

// ---------- x fp32 -> bf16 ----------
__global__ __launch_bounds__(256) void xconv(const float* __restrict__ x, unsigned short* __restrict__ xb) {
  const int i = (blockIdx.x * 256 + threadIdx.x) * 8;
  const float4 a = *(const float4*)&x[i];
  const float4 b = *(const float4*)&x[i + 4];
  uint4 o;
  o.x = pack_bf16(a.x, a.y);
  o.y = pack_bf16(a.z, a.w);
  o.z = pack_bf16(b.x, b.y);
  o.w = pack_bf16(b.z, b.w);
  *(uint4*)&xb[i] = o;
}

// ---------- bf16 MFMA GEMM: Y = A[M,1024] @ Bt[n][k]^T + bias ----------
template <bool BF16OUT>
__global__ __launch_bounds__(256) void gemm_mfma(const unsigned short* __restrict__ A,
                                                 const unsigned short* __restrict__ B0,
                                                 const unsigned short* __restrict__ B1,
                                                 const unsigned short* __restrict__ B2,
                                                 const float* __restrict__ bi0, const float* __restrict__ bi1,
                                                 const float* __restrict__ bi2,
                                                 void* __restrict__ Y0, void* __restrict__ Y1,
                                                 void* __restrict__ Y2) {
  const int z = blockIdx.z;
  const unsigned short* Bt = z == 0 ? B0 : z == 1 ? B1 : B2;
  const float* bias = z == 0 ? bi0 : z == 1 ? bi1 : bi2;
  void* Y = z == 0 ? Y0 : z == 1 ? Y1 : Y2;
  __shared__ unsigned short As[8192];
  __shared__ unsigned short Bs[8192];
  const int tid = threadIdx.x;
  const int m0 = blockIdx.y << 7, n0 = blockIdx.x << 7;
  const int w = tid >> 6, l = tid & 63, g = l >> 4, c = l & 15;
  const int wm = (w >> 1) << 6, wn = (w & 1) << 6;
  const int srow = tid >> 3;
  const int skel = ((tid & 7) ^ (srow & 7)) << 3;
  const unsigned short* ga = &A[(size_t)(m0 + srow) * 1024 + skel];
  const unsigned short* gb = &Bt[(size_t)(n0 + srow) * 1024 + skel];
  unsigned short* la = &As[tid << 3];
  unsigned short* lb = &Bs[tid << 3];
  f32x4 acc[4][4];
#pragma unroll
  for (int i = 0; i < 4; ++i)
#pragma unroll
    for (int j = 0; j < 4; ++j) acc[i][j] = {0.f, 0.f, 0.f, 0.f};
  for (int k0 = 0; k0 < 1024; k0 += 64) {
    __syncthreads();
#pragma unroll
    for (int a = 0; a < 4; ++a) {
      gld_lds16(ga + (size_t)(a << 5) * 1024 + k0, la + (a << 11));
      gld_lds16(gb + (size_t)(a << 5) * 1024 + k0, lb + (a << 11));
    }
    __syncthreads();
#pragma unroll
    for (int kc = 0; kc < 2; ++kc) {
      bf16x8 af[4], bfr[4];
#pragma unroll
      for (int mf = 0; mf < 4; ++mf) {
        const int m = wm + (mf << 4) + c;
        af[mf] = *(const bf16x8*)&As[((m << 6) + (kc << 5) + (g << 3)) ^ ((m & 7) << 3)];
      }
#pragma unroll
      for (int nf = 0; nf < 4; ++nf) {
        const int n = wn + (nf << 4) + c;
        bfr[nf] = *(const bf16x8*)&Bs[((n << 6) + (kc << 5) + (g << 3)) ^ ((n & 7) << 3)];
      }
#pragma unroll
      for (int mf = 0; mf < 4; ++mf)
#pragma unroll
        for (int nf = 0; nf < 4; ++nf)
          acc[mf][nf] = __builtin_amdgcn_mfma_f32_16x16x32_bf16(af[mf], bfr[nf], acc[mf][nf], 0, 0, 0);
    }
  }
#pragma unroll
  for (int nf = 0; nf < 4; ++nf) {
    const int n = n0 + wn + (nf << 4) + c;
    const float bb = bias[n];
#pragma unroll
    for (int mf = 0; mf < 4; ++mf) {
      const int mrow = m0 + wm + (mf << 4) + (g << 2);
#pragma unroll
      for (int r = 0; r < 4; ++r) {
        const float val = acc[mf][nf][r] + bb;
        if (BF16OUT)
          ((unsigned short*)Y)[((size_t)(mrow + r) << 10) + n] = f2b(val);
        else
          ((float*)Y)[((size_t)(mrow + r) << 10) + n] = val;
      }
    }
  }
}

// ---------- bf16 transpose: Vb [b][t][d] -> Vt [b][d][t] ----------
__global__ __launch_bounds__(256) void transpose_bf16(const unsigned short* __restrict__ Vb,
                                                      unsigned short* __restrict__ Vt) {
  __shared__ unsigned short tile[64][73];
  const int b = blockIdx.z;
  const int t0 = blockIdx.x << 6, d0 = blockIdx.y << 6;
  const int row = threadIdx.x >> 2, cq = (threadIdx.x & 3) << 4;
  const unsigned short* src = &Vb[((size_t)((b << 11) + t0 + row) << 10) + d0 + cq];
  const uint4 va = *(const uint4*)&src[0];
  const uint4 vb2 = *(const uint4*)&src[8];
  const unsigned in[8] = {va.x, va.y, va.z, va.w, vb2.x, vb2.y, vb2.z, vb2.w};
#pragma unroll
  for (int e = 0; e < 8; ++e) {
    tile[row][cq + 2 * e] = (unsigned short)in[e];
    tile[row][cq + 2 * e + 1] = (unsigned short)(in[e] >> 16);
  }
  __syncthreads();
  unsigned o[8];
#pragma unroll
  for (int e = 0; e < 8; ++e)
    o[e] = (unsigned)tile[cq + 2 * e][row] | ((unsigned)tile[cq + 2 * e + 1][row] << 16);
  unsigned short* dst = &Vt[((size_t)((b << 10) + d0 + row) << 11) + t0 + cq];
  uint4 lo, hi;
  lo.x = o[0]; lo.y = o[1]; lo.z = o[2]; lo.w = o[3];
  hi.x = o[4]; hi.y = o[5]; hi.z = o[6]; hi.w = o[7];
  *(uint4*)&dst[0] = lo;
  *(uint4*)&dst[8] = hi;
}

// ---------- per-32-row block sums of V ----------
__global__ __launch_bounds__(256) void vblk32(const unsigned short* __restrict__ Vb,
                                              float* __restrict__ Blk) {
  const int b = blockIdx.x >> 6, t = blockIdx.x & 63;
  const int d4 = threadIdx.x << 2;
  float s0 = 0.f, s1 = 0.f, s2 = 0.f, s3 = 0.f;
  for (int j = 0; j < 32; ++j) {
    const uint2 v = *(const uint2*)&Vb[((size_t)((b << 11) + (t << 5) + j) << 10) + d4];
    s0 += blo(v.x); s1 += bhi(v.x); s2 += blo(v.y); s3 += bhi(v.y);
  }
  float4 o = {s0, s1, s2, s3};
  *(float4*)&Blk[((size_t)((b << 6) + t) << 10) + d4] = o;
}

// ---------- suffix over 64 tiles ----------
__global__ __launch_bounds__(256) void vsuffix32(const float* __restrict__ Blk, float* __restrict__ Suf) {
  const int idx = blockIdx.x * 256 + threadIdx.x;
  const int b = idx >> 10, d = idx & 1023;
  float s = 0.f;
  Suf[((size_t)(b * 65 + 64) << 10) + d] = 0.f;
  for (int t = 63; t >= 0; --t) {
    s += Blk[((size_t)((b << 6) + t) << 10) + d];
    Suf[((size_t)(b * 65 + t) << 10) + d] = s;
  }
}

// ---------- LDS-staged MFMA attention, head-axis softmax ----------
// Block = 8 waves (iw: 16-row sub-tile, dh: 8-head half), i-tile 64. Per 32-j tile:
// cooperative K/V staging (swizzled global_load_lds), per-wave QK^T on own heads,
// Sigma-exp exchange with dh-partner via LDS, bpermute weight relayout, PV MFMA.
// launch_bounds(512,1): 1 block/CU (LDS-forced anyway) -> 256 VGPR cap, no spill.
__global__ __launch_bounds__(512, 1) void attn_v5(const unsigned short* __restrict__ Qb,
                                                  const unsigned short* __restrict__ Kb,
                                                  const unsigned short* __restrict__ Vt,
                                                  float* __restrict__ AO) {
  __shared__ unsigned short Ks[32 * 1024];  // 64 KB, chunk-XOR swizzled
  __shared__ unsigned short Vs[1024 * 32];  // 64 KB, (d>>1)&3 swizzled
  __shared__ float Sx[4096];                // 16 KB partial-sum exchange

  const int s = blockIdx.x;
  const int it = 31 - blockIdx.y;  // heavy-first
  const int b = blockIdx.z;
  const int nt = 2 * it + 2;
  const int nc = (nt + TPC - 1) / TPC;
  if (s >= nc) return;
  const int i0 = it << 6;
  const int tid = threadIdx.x;
  const int w = tid >> 6, l = tid & 63, g = l >> 4, c = l & 15;
  const int iw = w >> 1, dh = w & 1;
  const int i0w = i0 + (iw << 4);
  const int hs = dh << 3;
  const int ib = i0w + c;

  // own-head Q B-frags (64 VGPR)
  bf16x8 qf[16];
  const unsigned short* qbase = &Qb[((size_t)((b << 11) + i0w + c) << 10) + (g << 3)];
#pragma unroll
  for (int hh = 0; hh < 8; ++hh) {
    qf[2 * hh] = *(const bf16x8*)&qbase[(hs + hh) << 6];
    qf[2 * hh + 1] = *(const bf16x8*)&qbase[((hs + hh) << 6) + 32];
  }

  f32x4 acc[8][4];
#pragma unroll
  for (int hh = 0; hh < 8; ++hh)
#pragma unroll
    for (int cc = 0; cc < 4; ++cc) acc[hh][cc] = {0.f, 0.f, 0.f, 0.f};

  const float SC = 0.04508422f;  // log2(e)/32
  const int adrA = (((g & 1) << 5) | c) << 2;
  const int adrB = adrA + 64;
  const bool tsel = g >= 2;
  const int sxo = ((iw << 1) + dh) << 9;
  const int sxp = ((iw << 1) + (1 - dh)) << 9;

  for (int ts = s; ts < nt; ts += nc) {
    const int j0 = ts << 5;
    __syncthreads();  // prior tile's LDS reads complete
    // stage K and V (global_load_lds w16, pre-swizzled source)
#pragma unroll
    for (int kk = 0; kk < 8; ++kk) {
      const int q = tid + (kk << 9);
      const int row = q >> 7, cc8 = q & 127;
      const int scc = cc8 ^ (row & 7);
      gld_lds16(&Kb[((size_t)((b << 11) + j0 + row) << 10) + (scc << 3)], &Ks[q << 3]);
    }
#pragma unroll
    for (int kk = 0; kk < 8; ++kk) {
      const int q = tid + (kk << 9);
      const int d = q >> 2, jc = q & 3;
      const int jcg = jc ^ ((d >> 1) & 3);
      gld_lds16(&Vt[(((size_t)((b << 10) + d)) << 11) + j0 + (jcg << 3)], &Vs[q << 3]);
    }
    __syncthreads();  // staging complete

    const bool live = (j0 <= i0w + 15);
    unsigned Ea[8], Eb[8], Ec[8], Ed[8];
    if (live) {
#pragma unroll
      for (int tau = 0; tau < 2; ++tau) {
        const int krow = (tau << 4) + c;
        const int kx = krow & 7;
        f32x4 ps = {0.f, 0.f, 0.f, 0.f};
#pragma unroll
        for (int hh = 0; hh < 8; ++hh) {
          const int e8 = (hs + hh) << 3;
          const bf16x8 k0 = *(const bf16x8*)&Ks[((krow << 7) + ((e8 + g) ^ kx)) << 3];
          const bf16x8 k1 = *(const bf16x8*)&Ks[((krow << 7) + ((e8 + 4 + g) ^ kx)) << 3];
          f32x4 a = {0.f, 0.f, 0.f, 0.f};
          a = __builtin_amdgcn_mfma_f32_16x16x32_bf16(k0, qf[2 * hh], a, 0, 0, 0);
          a = __builtin_amdgcn_mfma_f32_16x16x32_bf16(k1, qf[2 * hh + 1], a, 0, 0, 0);
          const float e0 = exp2f(a[0] * SC), e1 = exp2f(a[1] * SC);
          const float e2 = exp2f(a[2] * SC), e3 = exp2f(a[3] * SC);
          ps[0] += e0; ps[1] += e1; ps[2] += e2; ps[3] += e3;
          const unsigned p0 = pack_bf16(e0, e1), p1 = pack_bf16(e2, e3);
          if (tau == 0) { Ea[hh] = p0; Eb[hh] = p1; }
          else { Ec[hh] = p0; Ed[hh] = p1; }
        }
        *(f32x4*)&Sx[sxo + (tau << 8) + (l << 2)] = ps;
      }
    }
    __syncthreads();  // Sx ready
    if (live) {
      const f32x4 o0 = *(const f32x4*)&Sx[sxo + (l << 2)];
      const f32x4 o1 = *(const f32x4*)&Sx[sxo + 256 + (l << 2)];
      const f32x4 q0 = *(const f32x4*)&Sx[sxp + (l << 2)];
      const f32x4 q1 = *(const f32x4*)&Sx[sxp + 256 + (l << 2)];
      f32x4 inv0, inv1;
#pragma unroll
      for (int r = 0; r < 4; ++r) {
        inv0[r] = __builtin_amdgcn_rcpf(o0[r] + q0[r]);
        inv1[r] = __builtin_amdgcn_rcpf(o1[r] + q1[r]);
      }
      const int jb = j0 + (g << 2);
      const bool ma0 = jb + 0 > ib, ma1 = jb + 1 > ib, ma2 = jb + 2 > ib, ma3 = jb + 3 > ib;
      const bool mb0 = jb + 16 > ib, mb1 = jb + 17 > ib, mb2 = jb + 18 > ib, mb3 = jb + 19 > ib;
#pragma unroll
      for (int hh = 0; hh < 8; ++hh) {
        const float wa0 = ma0 ? 0.0625f : blo(Ea[hh]) * inv0[0];
        const float wa1 = ma1 ? 0.0625f : bhi(Ea[hh]) * inv0[1];
        const float wa2 = ma2 ? 0.0625f : blo(Eb[hh]) * inv0[2];
        const float wa3 = ma3 ? 0.0625f : bhi(Eb[hh]) * inv0[3];
        const float wc0 = mb0 ? 0.0625f : blo(Ec[hh]) * inv1[0];
        const float wc1 = mb1 ? 0.0625f : bhi(Ec[hh]) * inv1[1];
        const float wc2 = mb2 ? 0.0625f : blo(Ed[hh]) * inv1[2];
        const float wc3 = mb3 ? 0.0625f : bhi(Ed[hh]) * inv1[3];
        Ea[hh] = pack_bf16(wa0, wa1);
        Eb[hh] = pack_bf16(wa2, wa3);
        Ec[hh] = pack_bf16(wc0, wc1);
        Ed[hh] = pack_bf16(wc2, wc3);
      }
    } else {
#pragma unroll
      for (int hh = 0; hh < 8; ++hh) {
        Ea[hh] = 0x3D803D80u; Eb[hh] = 0x3D803D80u;
        Ec[hh] = 0x3D803D80u; Ed[hh] = 0x3D803D80u;
      }
    }
    // bpermute relayout + PV (V from LDS)
#pragma unroll
    for (int hh = 0; hh < 8; ++hh) {
      const int h = hs + hh;
      const unsigned a0A = __builtin_amdgcn_ds_bpermute(adrA, (int)Ea[hh]);
      const unsigned a1A = __builtin_amdgcn_ds_bpermute(adrA, (int)Eb[hh]);
      const unsigned c0A = __builtin_amdgcn_ds_bpermute(adrA, (int)Ec[hh]);
      const unsigned c1A = __builtin_amdgcn_ds_bpermute(adrA, (int)Ed[hh]);
      const unsigned a0B = __builtin_amdgcn_ds_bpermute(adrB, (int)Ea[hh]);
      const unsigned a1B = __builtin_amdgcn_ds_bpermute(adrB, (int)Eb[hh]);
      const unsigned c0B = __builtin_amdgcn_ds_bpermute(adrB, (int)Ec[hh]);
      const unsigned c1B = __builtin_amdgcn_ds_bpermute(adrB, (int)Ed[hh]);
      union { bf16x8 v; unsigned u[4]; } pa;
      pa.u[0] = tsel ? c0A : a0A;
      pa.u[1] = tsel ? c1A : a1A;
      pa.u[2] = tsel ? c0B : a0B;
      pa.u[3] = tsel ? c1B : a1B;
#pragma unroll
      for (int cc = 0; cc < 4; ++cc) {
        const int d = (h << 6) + (cc << 4) + c;
        const bf16x8 bv = *(const bf16x8*)&Vs[(((d << 2) + (g ^ ((d >> 1) & 3))) << 3)];
        acc[hh][cc] = __builtin_amdgcn_mfma_f32_16x16x32_bf16(pa.v, bv, acc[hh][cc], 0, 0, 0);
      }
    }
  }
  // epilogue: atomic accumulate into fp32 AO
#pragma unroll
  for (int hh = 0; hh < 8; ++hh)
#pragma unroll
    for (int cc = 0; cc < 4; ++cc)
#pragma unroll
      for (int r = 0; r < 4; ++r)
        atomicAdd(&AO[((size_t)((b << 11) + i0w + (g << 2) + r) << 10) + ((hs + hh) << 6) + (cc << 4) + c],
                  acc[hh][cc][r]);
}

// ---------- AO fp32 + (1/16)*suffix -> bf16 ----------
__global__ __launch_bounds__(256) void aocvt(const float* __restrict__ AO, const float* __restrict__ Suf,
                                             unsigned short* __restrict__ AOb) {
  const int i = (blockIdx.x * 256 + threadIdx.x) << 3;
  const int m = i >> 10;
  const int b = m >> 11, it = (m & 2047) >> 6;
  const int d0 = i & 1023;
  const float* sp = &Suf[((size_t)(b * 65 + 2 * it + 2) << 10) + d0];
  const float4 a0 = *(const float4*)&AO[i];
  const float4 a1 = *(const float4*)&AO[i + 4];
  const float4 s0 = *(const float4*)&sp[0];
  const float4 s1 = *(const float4*)&sp[4];
  uint4 o;
  o.x = pack_bf16(a0.x + 0.0625f * s0.x, a0.y + 0.0625f * s0.y);
  o.y = pack_bf16(a0.z + 0.0625f * s0.z, a0.w + 0.0625f * s0.w);
  o.z = pack_bf16(a1.x + 0.0625f * s1.x, a1.y + 0.0625f * s1.y);
  o.w = pack_bf16(a1.z + 0.0625f * s1.z, a1.w + 0.0625f * s1.w);
  *(uint4*)&AOb[i] = o;
}

extern "C" void kernel_launch(void* const* d_in, const int* in_sizes, int n_in,
                              void* d_out, int out_size, void* d_ws, size_t ws_size,
                              hipStream_t stream) {
  (void)in_sizes; (void)n_in; (void)out_size; (void)ws_size;
  const float* x = (const float*)d_in[0];
  const float* Wq = (const float*)d_in[1];
  const float* bq = (const float*)d_in[2];
  const float* Wk = (const float*)d_in[3];
  const float* bk = (const float*)d_in[4];
  const float* Wv = (const float*)d_in[5];
  const float* bv = (const float*)d_in[6];
  const float* Wo = (const float*)d_in[7];
  const float* bo = (const float*)d_in[8];
  float* out = (float*)d_out;
  char* ws = (char*)d_ws;

  const size_t MB = 1024 * 1024;
  unsigned short* xb  = (unsigned short*)(ws);            // 8MB; AOb aliases after projections
  unsigned short* Qb  = (unsigned short*)(ws + 8 * MB);   // 8MB
  unsigned short* Kb  = (unsigned short*)(ws + 16 * MB);  // 8MB
  unsigned short* Vb  = (unsigned short*)(ws + 24 * MB);  // 8MB
  unsigned short* Vt  = (unsigned short*)(ws + 32 * MB);  // 8MB
  unsigned short* Wqt = (unsigned short*)(ws + 40 * MB);  // 2MB each; Blk/Suf overlay Wqt/Wkt after proj
  unsigned short* Wkt = (unsigned short*)(ws + 42 * MB);
  unsigned short* Wvt = (unsigned short*)(ws + 44 * MB);
  unsigned short* Wot = (unsigned short*)(ws + 46 * MB);
  float* AO = (float*)(ws + 48 * MB);                     // 16MB fp32 accumulation
  float* Blk = (float*)(ws + 40 * MB);                    // 512KB (over Wqt)
  float* Suf = (float*)(ws + 40 * MB + 512 * 1024);       // 520KB (over Wqt/Wkt)
  unsigned short* AOb = xb;

  hipLaunchKernelGGL(wtrans, dim3(16, 16, 4), dim3(256), 0, stream,
                     Wq, Wk, Wv, Wo, Wqt, Wkt, Wvt, Wot);
  hipLaunchKernelGGL(xconv, dim3(2048), dim3(256), 0, stream, x, xb);
  hipLaunchKernelGGL((gemm_mfma<true>), dim3(8, 32, 3), dim3(256), 0, stream,
                     xb, Wqt, Wkt, Wvt, bq, bk, bv, (void*)Qb, (void*)Kb, (void*)Vb);
  hipLaunchKernelGGL(transpose_bf16, dim3(32, 16, 2), dim3(256), 0, stream, Vb, Vt);
  hipLaunchKernelGGL(vblk32, dim3(128), dim3(256), 0, stream, Vb, Blk);
  hipLaunchKernelGGL(vsuffix32, dim3(8), dim3(256), 0, stream, Blk, Suf);
  hipMemsetAsync(AO, 0, (size_t)B_ * T_ * D_ * sizeof(float), stream);
  hipLaunchKernelGGL(attn_v5, dim3(16, 32, 2), dim3(512), 0, stream, Qb, Kb, Vt, AO);
  hipLaunchKernelGGL(aocvt, dim3(2048), dim3(256), 0, stream, AO, Suf, AOb);
  hipLaunchKernelGGL((gemm_mfma<false>), dim3(8, 32, 1), dim3(256), 0, stream,
                     AOb, Wot, Wot, Wot, bo, bo, bo, (void*)out, (void*)out, (void*)out);
}

// Round 6
// 496.230 us; speedup vs baseline: 6.9301x; 1.0702x over previous
//
#include <hip/hip_runtime.h>
#include <hip/hip_bf16.h>

#define B_ 2
#define T_ 2048
#define D_ 1024
#define H_ 16

typedef __attribute__((ext_vector_type(8))) short bf16x8;
typedef __attribute__((ext_vector_type(4))) float f32x4;

__device__ __forceinline__ unsigned pack_bf16(float x, float y) {
  unsigned xb = __float_as_uint(x), yb = __float_as_uint(y);
  xb += 0x7fffu + ((xb >> 16) & 1u);
  yb += 0x7fffu + ((yb >> 16) & 1u);
  return (xb >> 16) | (yb & 0xffff0000u);
}
__device__ __forceinline__ unsigned short f2b(float x) {
  unsigned u = __float_as_uint(x);
  u += 0x7fffu + ((u >> 16) & 1u);
  return (unsigned short)(u >> 16);
}
__device__ __forceinline__ float blo(unsigned u) { return __uint_as_float(u << 16); }
__device__ __forceinline__ float bhi(unsigned u) { return __uint_as_float(u & 0xffff0000u); }

__device__ __forceinline__ void gld_lds16(const unsigned short* g, unsigned short* l) {
  __builtin_amdgcn_global_load_lds(
      (const __attribute__((address_space(1))) unsigned int*)g,
      (__attribute__((address_space(3))) unsigned int*)l, 16, 0, 0);
}

// ---------- weight transpose + convert: Wt[n][k] = bf16(W[k][n]), 4 weights ----------
__global__ __launch_bounds__(256) void wtrans(const float* __restrict__ W0, const float* __restrict__ W1,
                                              const float* __restrict__ W2, const float* __restrict__ W3,
                                              unsigned short* __restrict__ T0, unsigned short* __restrict__ T1,
                                              unsigned short* __restrict__ T2, unsigned short* __restrict__ T3) {
  const int z = blockIdx.z;
  const float* W = z == 0 ? W0 : z == 1 ? W1 : z == 2 ? W2 : W3;
  unsigned short* T = z == 0 ? T0 : z == 1 ? T1 : z == 2 ? T2 : T3;
  __shared__ unsigned short t[64][72];
  const int k0 = blockIdx.x << 6, n0 = blockIdx.y << 6;
  const int r = threadIdx.x >> 2, c16 = (threadIdx.x & 3) << 4;
#pragma unroll
  for (int e = 0; e < 4; ++e) {
    const float4 v = *(const float4*)&W[(size_t)(k0 + r) * 1024 + n0 + c16 + e * 4];
    t[r][c16 + e * 4 + 0] = f2b(v.x);
    t[r][c16 + e * 4 + 1] = f2b(v.y);
    t[r][c16 + e * 4 + 2] = f2b(v.z);
    t[r][c16 + e * 4 + 3] = f2b(v.w);
  }
  __syncthreads();
  unsigned short o[16];
#pragma unroll
  for (int e = 0; e < 16; ++e) o[e] = t[c16 + e][r];
  unsigned short* dst = &T[(size_t)(n0 + r) * 1024 + k0 + c16];
  *(uint4*)&dst[0] = *(uint4*)&o[0];
  *(uint4*)&dst[8] = *(uint4*)&o[8];
}

// ---------- x fp32 -> bf16 ----------
__global__ __launch_bounds__(256) void xconv(const float* __restrict__ x, unsigned short* __restrict__ xb) {
  const int i = (blockIdx.x * 256 + threadIdx.x) * 8;
  const float4 a = *(const float4*)&x[i];
  const float4 b = *(const float4*)&x[i + 4];
  uint4 o;
  o.x = pack_bf16(a.x, a.y);
  o.y = pack_bf16(a.z, a.w);
  o.z = pack_bf16(b.x, b.y);
  o.w = pack_bf16(b.z, b.w);
  *(uint4*)&xb[i] = o;
}

// ---------- bf16 MFMA GEMM: Y = A[M,1024] @ Bt[n][k]^T + bias ----------
template <bool BF16OUT>
__global__ __launch_bounds__(256) void gemm_mfma(const unsigned short* __restrict__ A,
                                                 const unsigned short* __restrict__ B0,
                                                 const unsigned short* __restrict__ B1,
                                                 const unsigned short* __restrict__ B2,
                                                 const float* __restrict__ bi0, const float* __restrict__ bi1,
                                                 const float* __restrict__ bi2,
                                                 void* __restrict__ Y0, void* __restrict__ Y1,
                                                 void* __restrict__ Y2) {
  const int z = blockIdx.z;
  const unsigned short* Bt = z == 0 ? B0 : z == 1 ? B1 : B2;
  const float* bias = z == 0 ? bi0 : z == 1 ? bi1 : bi2;
  void* Y = z == 0 ? Y0 : z == 1 ? Y1 : Y2;
  __shared__ unsigned short As[8192];
  __shared__ unsigned short Bs[8192];
  const int tid = threadIdx.x;
  const int m0 = blockIdx.y << 7, n0 = blockIdx.x << 7;
  const int w = tid >> 6, l = tid & 63, g = l >> 4, c = l & 15;
  const int wm = (w >> 1) << 6, wn = (w & 1) << 6;
  const int srow = tid >> 3;
  const int skel = ((tid & 7) ^ (srow & 7)) << 3;
  const unsigned short* ga = &A[(size_t)(m0 + srow) * 1024 + skel];
  const unsigned short* gb = &Bt[(size_t)(n0 + srow) * 1024 + skel];
  unsigned short* la = &As[tid << 3];
  unsigned short* lb = &Bs[tid << 3];
  f32x4 acc[4][4];
#pragma unroll
  for (int i = 0; i < 4; ++i)
#pragma unroll
    for (int j = 0; j < 4; ++j) acc[i][j] = {0.f, 0.f, 0.f, 0.f};
  for (int k0 = 0; k0 < 1024; k0 += 64) {
    __syncthreads();
#pragma unroll
    for (int a = 0; a < 4; ++a) {
      gld_lds16(ga + (size_t)(a << 5) * 1024 + k0, la + (a << 11));
      gld_lds16(gb + (size_t)(a << 5) * 1024 + k0, lb + (a << 11));
    }
    __syncthreads();
#pragma unroll
    for (int kc = 0; kc < 2; ++kc) {
      bf16x8 af[4], bfr[4];
#pragma unroll
      for (int mf = 0; mf < 4; ++mf) {
        const int m = wm + (mf << 4) + c;
        af[mf] = *(const bf16x8*)&As[((m << 6) + (kc << 5) + (g << 3)) ^ ((m & 7) << 3)];
      }
#pragma unroll
      for (int nf = 0; nf < 4; ++nf) {
        const int n = wn + (nf << 4) + c;
        bfr[nf] = *(const bf16x8*)&Bs[((n << 6) + (kc << 5) + (g << 3)) ^ ((n & 7) << 3)];
      }
#pragma unroll
      for (int mf = 0; mf < 4; ++mf)
#pragma unroll
        for (int nf = 0; nf < 4; ++nf)
          acc[mf][nf] = __builtin_amdgcn_mfma_f32_16x16x32_bf16(af[mf], bfr[nf], acc[mf][nf], 0, 0, 0);
    }
  }
#pragma unroll
  for (int nf = 0; nf < 4; ++nf) {
    const int n = n0 + wn + (nf << 4) + c;
    const float bb = bias[n];
#pragma unroll
    for (int mf = 0; mf < 4; ++mf) {
      const int mrow = m0 + wm + (mf << 4) + (g << 2);
#pragma unroll
      for (int r = 0; r < 4; ++r) {
        const float val = acc[mf][nf][r] + bb;
        if (BF16OUT)
          ((unsigned short*)Y)[((size_t)(mrow + r) << 10) + n] = f2b(val);
        else
          ((float*)Y)[((size_t)(mrow + r) << 10) + n] = val;
      }
    }
  }
}

// ---------- bf16 transpose: Vb [b][t][d] -> Vt [b][d][t] ----------
__global__ __launch_bounds__(256) void transpose_bf16(const unsigned short* __restrict__ Vb,
                                                      unsigned short* __restrict__ Vt) {
  __shared__ unsigned short tile[64][73];
  const int b = blockIdx.z;
  const int t0 = blockIdx.x << 6, d0 = blockIdx.y << 6;
  const int row = threadIdx.x >> 2, cq = (threadIdx.x & 3) << 4;
  const unsigned short* src = &Vb[((size_t)((b << 11) + t0 + row) << 10) + d0 + cq];
  const uint4 va = *(const uint4*)&src[0];
  const uint4 vb2 = *(const uint4*)&src[8];
  const unsigned in[8] = {va.x, va.y, va.z, va.w, vb2.x, vb2.y, vb2.z, vb2.w};
#pragma unroll
  for (int e = 0; e < 8; ++e) {
    tile[row][cq + 2 * e] = (unsigned short)in[e];
    tile[row][cq + 2 * e + 1] = (unsigned short)(in[e] >> 16);
  }
  __syncthreads();
  unsigned o[8];
#pragma unroll
  for (int e = 0; e < 8; ++e)
    o[e] = (unsigned)tile[cq + 2 * e][row] | ((unsigned)tile[cq + 2 * e + 1][row] << 16);
  unsigned short* dst = &Vt[((size_t)((b << 10) + d0 + row) << 11) + t0 + cq];
  uint4 lo, hi;
  lo.x = o[0]; lo.y = o[1]; lo.z = o[2]; lo.w = o[3];
  hi.x = o[4]; hi.y = o[5]; hi.z = o[6]; hi.w = o[7];
  *(uint4*)&dst[0] = lo;
  *(uint4*)&dst[8] = hi;
}

// ---------- per-32-row block sums of V ----------
__global__ __launch_bounds__(256) void vblk32(const unsigned short* __restrict__ Vb,
                                              float* __restrict__ Blk) {
  const int b = blockIdx.x >> 6, t = blockIdx.x & 63;
  const int d4 = threadIdx.x << 2;
  float s0 = 0.f, s1 = 0.f, s2 = 0.f, s3 = 0.f;
  for (int j = 0; j < 32; ++j) {
    const uint2 v = *(const uint2*)&Vb[((size_t)((b << 11) + (t << 5) + j) << 10) + d4];
    s0 += blo(v.x); s1 += bhi(v.x); s2 += blo(v.y); s3 += bhi(v.y);
  }
  float4 o = {s0, s1, s2, s3};
  *(float4*)&Blk[((size_t)((b << 6) + t) << 10) + d4] = o;
}

// ---------- suffix over 64 tiles ----------
__global__ __launch_bounds__(256) void vsuffix32(const float* __restrict__ Blk, float* __restrict__ Suf) {
  const int idx = blockIdx.x * 256 + threadIdx.x;
  const int b = idx >> 10, d = idx & 1023;
  float s = 0.f;
  Suf[((size_t)(b * 65 + 64) << 10) + d] = 0.f;
  for (int t = 63; t >= 0; --t) {
    s += Blk[((size_t)((b << 6) + t) << 10) + d];
    Suf[((size_t)(b * 65 + t) << 10) + d] = s;
  }
}

// ---------- attention v6: head-axis softmax, no staging, no relayout ----------
// Block = 8 waves, one 16-row i-tile; wave w owns heads {2w,2w+1}. Per 32-j step:
// QK via mfma(K,Q) (lane: i=c, j=4g+r for two 16-j tiles), exp2, Sigma-exp exchange
// across the 8 waves via double-buffered LDS (one barrier/step), then PV 16x16x32
// with k-order j={4g..4g+3, 16+4g..+3}: A-frag = lane-local packs of its own C-regs,
// B-frag = two 8B reads of Vt. K/V/Q direct from global (L2/L3-resident).
// launch_bounds(512,4): VGPR<=128 -> 16 waves/CU. Strips (TPC=4) + fp32 atomic AO.
__global__ __launch_bounds__(512, 4) void attn_v6(const unsigned short* __restrict__ Qb,
                                                  const unsigned short* __restrict__ Kb,
                                                  const unsigned short* __restrict__ Vt,
                                                  float* __restrict__ AO) {
  __shared__ f32x4 Sx[2][8][2][64];  // 32 KB double-buffered exchange

  const int s = blockIdx.x;
  const int it = 127 - blockIdx.y;  // heavy-first
  const int b = blockIdx.z;
  const int nt = (it + 2) >> 1;     // 32-j steps to cover diagonal
  const int nc = (nt + 3) >> 2;     // strips of <=4 steps
  if (s >= nc) return;
  const int i0 = it << 4;
  const int tid = threadIdx.x;
  const int w = tid >> 6, l = tid & 63, g = l >> 4, c = l & 15;
  const int ib = i0 + c;
  const float SC = 0.04508422f;  // log2(e)/32

  // Q B-frags for own 2 heads x 2 k-halves (16 VGPR)
  const unsigned short* qbase = &Qb[((size_t)((b << 11) + i0 + c) << 10) + (w << 7) + (g << 3)];
  bf16x8 qf[4];
  qf[0] = *(const bf16x8*)&qbase[0];
  qf[1] = *(const bf16x8*)&qbase[32];
  qf[2] = *(const bf16x8*)&qbase[64];
  qf[3] = *(const bf16x8*)&qbase[96];

  f32x4 acc[2][4];
#pragma unroll
  for (int hh = 0; hh < 2; ++hh)
#pragma unroll
    for (int cc = 0; cc < 4; ++cc) acc[hh][cc] = {0.f, 0.f, 0.f, 0.f};

  int buf = 0;
  for (int ts = s; ts < nt; ts += nc) {
    const int j0 = ts << 5;
    f32x4 ex0[2], ex1[2];
    f32x4 ps0 = {0.f, 0.f, 0.f, 0.f}, ps1 = {0.f, 0.f, 0.f, 0.f};
#pragma unroll
    for (int jt = 0; jt < 2; ++jt) {
      const unsigned short* kbase =
          &Kb[((size_t)((b << 11) + j0 + (jt << 4) + c) << 10) + (w << 7) + (g << 3)];
#pragma unroll
      for (int hh = 0; hh < 2; ++hh) {
        const bf16x8 k0 = *(const bf16x8*)&kbase[hh << 6];
        const bf16x8 k1 = *(const bf16x8*)&kbase[(hh << 6) + 32];
        f32x4 a = {0.f, 0.f, 0.f, 0.f};
        a = __builtin_amdgcn_mfma_f32_16x16x32_bf16(k0, qf[2 * hh], a, 0, 0, 0);
        a = __builtin_amdgcn_mfma_f32_16x16x32_bf16(k1, qf[2 * hh + 1], a, 0, 0, 0);
        f32x4 e;
#pragma unroll
        for (int r = 0; r < 4; ++r) e[r] = exp2f(a[r] * SC);
        if (jt == 0) { ex0[hh] = e; ps0 += e; }
        else { ex1[hh] = e; ps1 += e; }
      }
    }
    Sx[buf][w][0][l] = ps0;
    Sx[buf][w][1][l] = ps1;
    __syncthreads();
    f32x4 s0 = Sx[buf][0][0][l];
    f32x4 s1 = Sx[buf][0][1][l];
#pragma unroll
    for (int d = 1; d < 8; ++d) {
      s0 += Sx[buf][d][0][l];
      s1 += Sx[buf][d][1][l];
    }
    buf ^= 1;
    f32x4 inv0, inv1;
#pragma unroll
    for (int r = 0; r < 4; ++r) {
      inv0[r] = __builtin_amdgcn_rcpf(s0[r]);
      inv1[r] = __builtin_amdgcn_rcpf(s1[r]);
    }
    const int jb = j0 + (g << 2);
#pragma unroll
    for (int hh = 0; hh < 2; ++hh) {
      float w0[4], w1[4];
#pragma unroll
      for (int r = 0; r < 4; ++r) {
        w0[r] = (jb + r > ib) ? 0.0625f : ex0[hh][r] * inv0[r];
        w1[r] = (jb + 16 + r > ib) ? 0.0625f : ex1[hh][r] * inv1[r];
      }
      union { bf16x8 v; unsigned u[4]; } pa;
      pa.u[0] = pack_bf16(w0[0], w0[1]);
      pa.u[1] = pack_bf16(w0[2], w0[3]);
      pa.u[2] = pack_bf16(w1[0], w1[1]);
      pa.u[3] = pack_bf16(w1[2], w1[3]);
      const unsigned short* vb = &Vt[((size_t)((b << 10) + (w << 7) + (hh << 6)) << 11)];
#pragma unroll
      for (int cc = 0; cc < 4; ++cc) {
        const unsigned short* vr = &vb[((size_t)((cc << 4) + c) << 11) + j0 + (g << 2)];
        const uint2 lo = *(const uint2*)&vr[0];
        const uint2 hi = *(const uint2*)&vr[16];
        union { bf16x8 v; unsigned u[4]; } vf;
        vf.u[0] = lo.x; vf.u[1] = lo.y; vf.u[2] = hi.x; vf.u[3] = hi.y;
        acc[hh][cc] = __builtin_amdgcn_mfma_f32_16x16x32_bf16(pa.v, vf.v, acc[hh][cc], 0, 0, 0);
      }
    }
  }
  // epilogue: atomic accumulate into fp32 AO
#pragma unroll
  for (int hh = 0; hh < 2; ++hh)
#pragma unroll
    for (int cc = 0; cc < 4; ++cc) {
      const int d = (w << 7) + (hh << 6) + (cc << 4) + c;
#pragma unroll
      for (int r = 0; r < 4; ++r)
        atomicAdd(&AO[((size_t)((b << 11) + i0 + (g << 2) + r) << 10) + d], acc[hh][cc][r]);
    }
}

// ---------- AO fp32 + (1/16)*suffix -> bf16 (suffix from 32-tile (i>>5)+1) ----------
__global__ __launch_bounds__(256) void aocvt(const float* __restrict__ AO, const float* __restrict__ Suf,
                                             unsigned short* __restrict__ AOb) {
  const int i = (blockIdx.x * 256 + threadIdx.x) << 3;
  const int m = i >> 10;
  const int b = m >> 11;
  const int sufidx = ((m & 2047) >> 5) + 1;
  const int d0 = i & 1023;
  const float* sp = &Suf[((size_t)(b * 65 + sufidx) << 10) + d0];
  const float4 a0 = *(const float4*)&AO[i];
  const float4 a1 = *(const float4*)&AO[i + 4];
  const float4 s0 = *(const float4*)&sp[0];
  const float4 s1 = *(const float4*)&sp[4];
  uint4 o;
  o.x = pack_bf16(a0.x + 0.0625f * s0.x, a0.y + 0.0625f * s0.y);
  o.y = pack_bf16(a0.z + 0.0625f * s0.z, a0.w + 0.0625f * s0.w);
  o.z = pack_bf16(a1.x + 0.0625f * s1.x, a1.y + 0.0625f * s1.y);
  o.w = pack_bf16(a1.z + 0.0625f * s1.z, a1.w + 0.0625f * s1.w);
  *(uint4*)&AOb[i] = o;
}

extern "C" void kernel_launch(void* const* d_in, const int* in_sizes, int n_in,
                              void* d_out, int out_size, void* d_ws, size_t ws_size,
                              hipStream_t stream) {
  (void)in_sizes; (void)n_in; (void)out_size; (void)ws_size;
  const float* x = (const float*)d_in[0];
  const float* Wq = (const float*)d_in[1];
  const float* bq = (const float*)d_in[2];
  const float* Wk = (const float*)d_in[3];
  const float* bk = (const float*)d_in[4];
  const float* Wv = (const float*)d_in[5];
  const float* bv = (const float*)d_in[6];
  const float* Wo = (const float*)d_in[7];
  const float* bo = (const float*)d_in[8];
  float* out = (float*)d_out;
  char* ws = (char*)d_ws;

  const size_t MB = 1024 * 1024;
  unsigned short* xb  = (unsigned short*)(ws);            // 8MB; AOb aliases after projections
  unsigned short* Qb  = (unsigned short*)(ws + 8 * MB);   // 8MB
  unsigned short* Kb  = (unsigned short*)(ws + 16 * MB);  // 8MB
  unsigned short* Vb  = (unsigned short*)(ws + 24 * MB);  // 8MB
  unsigned short* Vt  = (unsigned short*)(ws + 32 * MB);  // 8MB
  unsigned short* Wqt = (unsigned short*)(ws + 40 * MB);  // 2MB each; Blk/Suf overlay Wqt/Wkt after proj
  unsigned short* Wkt = (unsigned short*)(ws + 42 * MB);
  unsigned short* Wvt = (unsigned short*)(ws + 44 * MB);
  unsigned short* Wot = (unsigned short*)(ws + 46 * MB);
  float* AO = (float*)(ws + 48 * MB);                     // 16MB fp32 accumulation
  float* Blk = (float*)(ws + 40 * MB);                    // 512KB (over Wqt)
  float* Suf = (float*)(ws + 40 * MB + 512 * 1024);       // 520KB (over Wqt/Wkt)
  unsigned short* AOb = xb;

  hipLaunchKernelGGL(wtrans, dim3(16, 16, 4), dim3(256), 0, stream,
                     Wq, Wk, Wv, Wo, Wqt, Wkt, Wvt, Wot);
  hipLaunchKernelGGL(xconv, dim3(2048), dim3(256), 0, stream, x, xb);
  hipLaunchKernelGGL((gemm_mfma<true>), dim3(8, 32, 3), dim3(256), 0, stream,
                     xb, Wqt, Wkt, Wvt, bq, bk, bv, (void*)Qb, (void*)Kb, (void*)Vb);
  hipLaunchKernelGGL(transpose_bf16, dim3(32, 16, 2), dim3(256), 0, stream, Vb, Vt);
  hipLaunchKernelGGL(vblk32, dim3(128), dim3(256), 0, stream, Vb, Blk);
  hipLaunchKernelGGL(vsuffix32, dim3(8), dim3(256), 0, stream, Blk, Suf);
  hipMemsetAsync(AO, 0, (size_t)B_ * T_ * D_ * sizeof(float), stream);
  hipLaunchKernelGGL(attn_v6, dim3(16, 128, 2), dim3(512), 0, stream, Qb, Kb, Vt, AO);
  hipLaunchKernelGGL(aocvt, dim3(2048), dim3(256), 0, stream, AO, Suf, AOb);
  hipLaunchKernelGGL((gemm_mfma<false>), dim3(8, 32, 1), dim3(256), 0, stream,
                     AOb, Wot, Wot, Wot, bo, bo, bo, (void*)out, (void*)out, (void*)out);
}

// Round 7
// 324.425 us; speedup vs baseline: 10.6001x; 1.5296x over previous
//
#include <hip/hip_runtime.h>
#include <hip/hip_bf16.h>

#define B_ 2
#define T_ 2048
#define D_ 1024
#define H_ 16

typedef __attribute__((ext_vector_type(8))) short bf16x8;
typedef __attribute__((ext_vector_type(4))) float f32x4;

__device__ __forceinline__ unsigned pack_bf16(float x, float y) {
  unsigned xb = __float_as_uint(x), yb = __float_as_uint(y);
  xb += 0x7fffu + ((xb >> 16) & 1u);
  yb += 0x7fffu + ((yb >> 16) & 1u);
  return (xb >> 16) | (yb & 0xffff0000u);
}
__device__ __forceinline__ unsigned short f2b(float x) {
  unsigned u = __float_as_uint(x);
  u += 0x7fffu + ((u >> 16) & 1u);
  return (unsigned short)(u >> 16);
}
__device__ __forceinline__ float blo(unsigned u) { return __uint_as_float(u << 16); }
__device__ __forceinline__ float bhi(unsigned u) { return __uint_as_float(u & 0xffff0000u); }

__device__ __forceinline__ void gld_lds16(const unsigned short* g, unsigned short* l) {
  __builtin_amdgcn_global_load_lds(
      (const __attribute__((address_space(1))) unsigned int*)g,
      (__attribute__((address_space(3))) unsigned int*)l, 16, 0, 0);
}

// ---------- weight transpose + convert: Wt[n][k] = bf16(W[k][n]), 4 weights ----------
__global__ __launch_bounds__(256) void wtrans(const float* __restrict__ W0, const float* __restrict__ W1,
                                              const float* __restrict__ W2, const float* __restrict__ W3,
                                              unsigned short* __restrict__ T0, unsigned short* __restrict__ T1,
                                              unsigned short* __restrict__ T2, unsigned short* __restrict__ T3) {
  const int z = blockIdx.z;
  const float* W = z == 0 ? W0 : z == 1 ? W1 : z == 2 ? W2 : W3;
  unsigned short* T = z == 0 ? T0 : z == 1 ? T1 : z == 2 ? T2 : T3;
  __shared__ unsigned short t[64][72];
  const int k0 = blockIdx.x << 6, n0 = blockIdx.y << 6;
  const int r = threadIdx.x >> 2, c16 = (threadIdx.x & 3) << 4;
#pragma unroll
  for (int e = 0; e < 4; ++e) {
    const float4 v = *(const float4*)&W[(size_t)(k0 + r) * 1024 + n0 + c16 + e * 4];
    t[r][c16 + e * 4 + 0] = f2b(v.x);
    t[r][c16 + e * 4 + 1] = f2b(v.y);
    t[r][c16 + e * 4 + 2] = f2b(v.z);
    t[r][c16 + e * 4 + 3] = f2b(v.w);
  }
  __syncthreads();
  unsigned short o[16];
#pragma unroll
  for (int e = 0; e < 16; ++e) o[e] = t[c16 + e][r];
  unsigned short* dst = &T[(size_t)(n0 + r) * 1024 + k0 + c16];
  *(uint4*)&dst[0] = *(uint4*)&o[0];
  *(uint4*)&dst[8] = *(uint4*)&o[8];
}

// ---------- x fp32 -> bf16 ----------
__global__ __launch_bounds__(256) void xconv(const float* __restrict__ x, unsigned short* __restrict__ xb) {
  const int i = (blockIdx.x * 256 + threadIdx.x) * 8;
  const float4 a = *(const float4*)&x[i];
  const float4 b = *(const float4*)&x[i + 4];
  uint4 o;
  o.x = pack_bf16(a.x, a.y);
  o.y = pack_bf16(a.z, a.w);
  o.z = pack_bf16(b.x, b.y);
  o.w = pack_bf16(b.z, b.w);
  *(uint4*)&xb[i] = o;
}

// ---------- bf16 MFMA GEMM: Y = A[M,1024] @ Bt[n][k]^T + bias ----------
template <bool BF16OUT>
__global__ __launch_bounds__(256) void gemm_mfma(const unsigned short* __restrict__ A,
                                                 const unsigned short* __restrict__ B0,
                                                 const unsigned short* __restrict__ B1,
                                                 const unsigned short* __restrict__ B2,
                                                 const float* __restrict__ bi0, const float* __restrict__ bi1,
                                                 const float* __restrict__ bi2,
                                                 void* __restrict__ Y0, void* __restrict__ Y1,
                                                 void* __restrict__ Y2) {
  const int z = blockIdx.z;
  const unsigned short* Bt = z == 0 ? B0 : z == 1 ? B1 : B2;
  const float* bias = z == 0 ? bi0 : z == 1 ? bi1 : bi2;
  void* Y = z == 0 ? Y0 : z == 1 ? Y1 : Y2;
  __shared__ unsigned short As[8192];
  __shared__ unsigned short Bs[8192];
  const int tid = threadIdx.x;
  const int m0 = blockIdx.y << 7, n0 = blockIdx.x << 7;
  const int w = tid >> 6, l = tid & 63, g = l >> 4, c = l & 15;
  const int wm = (w >> 1) << 6, wn = (w & 1) << 6;
  const int srow = tid >> 3;
  const int skel = ((tid & 7) ^ (srow & 7)) << 3;
  const unsigned short* ga = &A[(size_t)(m0 + srow) * 1024 + skel];
  const unsigned short* gb = &Bt[(size_t)(n0 + srow) * 1024 + skel];
  unsigned short* la = &As[tid << 3];
  unsigned short* lb = &Bs[tid << 3];
  f32x4 acc[4][4];
#pragma unroll
  for (int i = 0; i < 4; ++i)
#pragma unroll
    for (int j = 0; j < 4; ++j) acc[i][j] = {0.f, 0.f, 0.f, 0.f};
  for (int k0 = 0; k0 < 1024; k0 += 64) {
    __syncthreads();
#pragma unroll
    for (int a = 0; a < 4; ++a) {
      gld_lds16(ga + (size_t)(a << 5) * 1024 + k0, la + (a << 11));
      gld_lds16(gb + (size_t)(a << 5) * 1024 + k0, lb + (a << 11));
    }
    __syncthreads();
#pragma unroll
    for (int kc = 0; kc < 2; ++kc) {
      bf16x8 af[4], bfr[4];
#pragma unroll
      for (int mf = 0; mf < 4; ++mf) {
        const int m = wm + (mf << 4) + c;
        af[mf] = *(const bf16x8*)&As[((m << 6) + (kc << 5) + (g << 3)) ^ ((m & 7) << 3)];
      }
#pragma unroll
      for (int nf = 0; nf < 4; ++nf) {
        const int n = wn + (nf << 4) + c;
        bfr[nf] = *(const bf16x8*)&Bs[((n << 6) + (kc << 5) + (g << 3)) ^ ((n & 7) << 3)];
      }
#pragma unroll
      for (int mf = 0; mf < 4; ++mf)
#pragma unroll
        for (int nf = 0; nf < 4; ++nf)
          acc[mf][nf] = __builtin_amdgcn_mfma_f32_16x16x32_bf16(af[mf], bfr[nf], acc[mf][nf], 0, 0, 0);
    }
  }
#pragma unroll
  for (int nf = 0; nf < 4; ++nf) {
    const int n = n0 + wn + (nf << 4) + c;
    const float bb = bias[n];
#pragma unroll
    for (int mf = 0; mf < 4; ++mf) {
      const int mrow = m0 + wm + (mf << 4) + (g << 2);
#pragma unroll
      for (int r = 0; r < 4; ++r) {
        const float val = acc[mf][nf][r] + bb;
        if (BF16OUT)
          ((unsigned short*)Y)[((size_t)(mrow + r) << 10) + n] = f2b(val);
        else
          ((float*)Y)[((size_t)(mrow + r) << 10) + n] = val;
      }
    }
  }
}

// ---------- bf16 transpose: Vb [b][t][d] -> Vt [b][d][t] ----------
__global__ __launch_bounds__(256) void transpose_bf16(const unsigned short* __restrict__ Vb,
                                                      unsigned short* __restrict__ Vt) {
  __shared__ unsigned short tile[64][73];
  const int b = blockIdx.z;
  const int t0 = blockIdx.x << 6, d0 = blockIdx.y << 6;
  const int row = threadIdx.x >> 2, cq = (threadIdx.x & 3) << 4;
  const unsigned short* src = &Vb[((size_t)((b << 11) + t0 + row) << 10) + d0 + cq];
  const uint4 va = *(const uint4*)&src[0];
  const uint4 vb2 = *(const uint4*)&src[8];
  const unsigned in[8] = {va.x, va.y, va.z, va.w, vb2.x, vb2.y, vb2.z, vb2.w};
#pragma unroll
  for (int e = 0; e < 8; ++e) {
    tile[row][cq + 2 * e] = (unsigned short)in[e];
    tile[row][cq + 2 * e + 1] = (unsigned short)(in[e] >> 16);
  }
  __syncthreads();
  unsigned o[8];
#pragma unroll
  for (int e = 0; e < 8; ++e)
    o[e] = (unsigned)tile[cq + 2 * e][row] | ((unsigned)tile[cq + 2 * e + 1][row] << 16);
  unsigned short* dst = &Vt[((size_t)((b << 10) + d0 + row) << 11) + t0 + cq];
  uint4 lo, hi;
  lo.x = o[0]; lo.y = o[1]; lo.z = o[2]; lo.w = o[3];
  hi.x = o[4]; hi.y = o[5]; hi.z = o[6]; hi.w = o[7];
  *(uint4*)&dst[0] = lo;
  *(uint4*)&dst[8] = hi;
}

// ---------- per-32-row block sums of V ----------
__global__ __launch_bounds__(256) void vblk32(const unsigned short* __restrict__ Vb,
                                              float* __restrict__ Blk) {
  const int b = blockIdx.x >> 6, t = blockIdx.x & 63;
  const int d4 = threadIdx.x << 2;
  float s0 = 0.f, s1 = 0.f, s2 = 0.f, s3 = 0.f;
  for (int j = 0; j < 32; ++j) {
    const uint2 v = *(const uint2*)&Vb[((size_t)((b << 11) + (t << 5) + j) << 10) + d4];
    s0 += blo(v.x); s1 += bhi(v.x); s2 += blo(v.y); s3 += bhi(v.y);
  }
  float4 o = {s0, s1, s2, s3};
  *(float4*)&Blk[((size_t)((b << 6) + t) << 10) + d4] = o;
}

// ---------- suffix over 64 tiles ----------
__global__ __launch_bounds__(256) void vsuffix32(const float* __restrict__ Blk, float* __restrict__ Suf) {
  const int idx = blockIdx.x * 256 + threadIdx.x;
  const int b = idx >> 10, d = idx & 1023;
  float s = 0.f;
  Suf[((size_t)(b * 65 + 64) << 10) + d] = 0.f;
  for (int t = 63; t >= 0; --t) {
    s += Blk[((size_t)((b << 6) + t) << 10) + d];
    Suf[((size_t)(b * 65 + t) << 10) + d] = s;
  }
}

// ---------- attention v7: head-axis softmax, strip partials, V-prefetch ----------
__global__ __launch_bounds__(512, 4) void attn_v7(const unsigned short* __restrict__ Qb,
                                                  const unsigned short* __restrict__ Kb,
                                                  const unsigned short* __restrict__ Vt,
                                                  unsigned short* __restrict__ P0,
                                                  unsigned short* __restrict__ P1,
                                                  unsigned short* __restrict__ P2,
                                                  unsigned short* __restrict__ P3) {
  __shared__ f32x4 Sx[2][8][2][64];  // 32 KB double-buffered exchange

  const int s = blockIdx.x;
  const int it = 127 - blockIdx.y;  // heavy-first
  const int b = blockIdx.z;
  const int nt = (it + 2) >> 1;
  const int i0 = it << 4;
  const int tid = threadIdx.x;
  const int w = tid >> 6, l = tid & 63, g = l >> 4, c = l & 15;
  const int ib = i0 + c;
  const float SC = 0.04508422f;  // log2(e)/32

  const unsigned short* qbase = &Qb[((size_t)((b << 11) + i0 + c) << 10) + (w << 7) + (g << 3)];
  bf16x8 qf[4];
  qf[0] = *(const bf16x8*)&qbase[0];
  qf[1] = *(const bf16x8*)&qbase[32];
  qf[2] = *(const bf16x8*)&qbase[64];
  qf[3] = *(const bf16x8*)&qbase[96];

  f32x4 acc[2][4];
#pragma unroll
  for (int hh = 0; hh < 2; ++hh)
#pragma unroll
    for (int cc = 0; cc < 4; ++cc) acc[hh][cc] = {0.f, 0.f, 0.f, 0.f};

  int buf = 0;
  for (int ts = s; ts < nt; ts += 4) {
    const int j0 = ts << 5;
    // V prefetch: latency hides under QK + exp + barrier
    uint2 vlo[2][4], vhi[2][4];
#pragma unroll
    for (int hh = 0; hh < 2; ++hh) {
      const unsigned short* vb = &Vt[((size_t)((b << 10) + (w << 7) + (hh << 6)) << 11)];
#pragma unroll
      for (int cc = 0; cc < 4; ++cc) {
        const unsigned short* vr = &vb[((size_t)((cc << 4) + c) << 11) + j0 + (g << 2)];
        vlo[hh][cc] = *(const uint2*)&vr[0];
        vhi[hh][cc] = *(const uint2*)&vr[16];
      }
    }
    f32x4 ex0[2], ex1[2];
    f32x4 ps0 = {0.f, 0.f, 0.f, 0.f}, ps1 = {0.f, 0.f, 0.f, 0.f};
#pragma unroll
    for (int jt = 0; jt < 2; ++jt) {
      const unsigned short* kbase =
          &Kb[((size_t)((b << 11) + j0 + (jt << 4) + c) << 10) + (w << 7) + (g << 3)];
#pragma unroll
      for (int hh = 0; hh < 2; ++hh) {
        const bf16x8 k0 = *(const bf16x8*)&kbase[hh << 6];
        const bf16x8 k1 = *(const bf16x8*)&kbase[(hh << 6) + 32];
        f32x4 a = {0.f, 0.f, 0.f, 0.f};
        a = __builtin_amdgcn_mfma_f32_16x16x32_bf16(k0, qf[2 * hh], a, 0, 0, 0);
        a = __builtin_amdgcn_mfma_f32_16x16x32_bf16(k1, qf[2 * hh + 1], a, 0, 0, 0);
        f32x4 e;
#pragma unroll
        for (int r = 0; r < 4; ++r) e[r] = exp2f(a[r] * SC);
        if (jt == 0) { ex0[hh] = e; ps0 += e; }
        else { ex1[hh] = e; ps1 += e; }
      }
    }
    Sx[buf][w][0][l] = ps0;
    Sx[buf][w][1][l] = ps1;
    __syncthreads();
    f32x4 s0 = Sx[buf][0][0][l];
    f32x4 s1 = Sx[buf][0][1][l];
#pragma unroll
    for (int d = 1; d < 8; ++d) {
      s0 += Sx[buf][d][0][l];
      s1 += Sx[buf][d][1][l];
    }
    buf ^= 1;
    f32x4 inv0, inv1;
#pragma unroll
    for (int r = 0; r < 4; ++r) {
      inv0[r] = __builtin_amdgcn_rcpf(s0[r]);
      inv1[r] = __builtin_amdgcn_rcpf(s1[r]);
    }
    const int jb = j0 + (g << 2);
#pragma unroll
    for (int hh = 0; hh < 2; ++hh) {
      float w0[4], w1[4];
#pragma unroll
      for (int r = 0; r < 4; ++r) {
        w0[r] = (jb + r > ib) ? 0.0625f : ex0[hh][r] * inv0[r];
        w1[r] = (jb + 16 + r > ib) ? 0.0625f : ex1[hh][r] * inv1[r];
      }
      union { bf16x8 v; unsigned u[4]; } pa;
      pa.u[0] = pack_bf16(w0[0], w0[1]);
      pa.u[1] = pack_bf16(w0[2], w0[3]);
      pa.u[2] = pack_bf16(w1[0], w1[1]);
      pa.u[3] = pack_bf16(w1[2], w1[3]);
#pragma unroll
      for (int cc = 0; cc < 4; ++cc) {
        union { bf16x8 v; unsigned u[4]; } vf;
        vf.u[0] = vlo[hh][cc].x; vf.u[1] = vlo[hh][cc].y;
        vf.u[2] = vhi[hh][cc].x; vf.u[3] = vhi[hh][cc].y;
        acc[hh][cc] = __builtin_amdgcn_mfma_f32_16x16x32_bf16(pa.v, vf.v, acc[hh][cc], 0, 0, 0);
      }
    }
  }
  unsigned short* AOp = s == 0 ? P0 : s == 1 ? P1 : s == 2 ? P2 : P3;
#pragma unroll
  for (int hh = 0; hh < 2; ++hh)
#pragma unroll
    for (int cc = 0; cc < 4; ++cc) {
      const int d = (w << 7) + (hh << 6) + (cc << 4) + c;
#pragma unroll
      for (int r = 0; r < 4; ++r)
        AOp[((size_t)((b << 11) + i0 + (g << 2) + r) << 10) + d] = f2b(acc[hh][cc][r]);
    }
}

// ---------- sum 4 bf16 partials + (1/16)*suffix -> bf16 ----------
__global__ __launch_bounds__(256) void aocvt(const unsigned short* __restrict__ P0,
                                             const unsigned short* __restrict__ P1,
                                             const unsigned short* __restrict__ P2,
                                             const unsigned short* __restrict__ P3,
                                             const float* __restrict__ Suf,
                                             unsigned short* __restrict__ AOb) {
  const int i = (blockIdx.x * 256 + threadIdx.x) << 3;
  const int m = i >> 10;
  const int b = m >> 11;
  const int sufidx = ((m & 2047) >> 5) + 1;
  const int d0 = i & 1023;
  const float* sp = &Suf[((size_t)(b * 65 + sufidx) << 10) + d0];
  const uint4 v0 = *(const uint4*)&P0[i];
  const uint4 v1 = *(const uint4*)&P1[i];
  const uint4 v2 = *(const uint4*)&P2[i];
  const uint4 v3 = *(const uint4*)&P3[i];
  const float4 s0 = *(const float4*)&sp[0];
  const float4 s1 = *(const float4*)&sp[4];
  uint4 o;
  o.x = pack_bf16(blo(v0.x) + blo(v1.x) + blo(v2.x) + blo(v3.x) + 0.0625f * s0.x,
                  bhi(v0.x) + bhi(v1.x) + bhi(v2.x) + bhi(v3.x) + 0.0625f * s0.y);
  o.y = pack_bf16(blo(v0.y) + blo(v1.y) + blo(v2.y) + blo(v3.y) + 0.0625f * s0.z,
                  bhi(v0.y) + bhi(v1.y) + bhi(v2.y) + bhi(v3.y) + 0.0625f * s0.w);
  o.z = pack_bf16(blo(v0.z) + blo(v1.z) + blo(v2.z) + blo(v3.z) + 0.0625f * s1.x,
                  bhi(v0.z) + bhi(v1.z) + bhi(v2.z) + bhi(v3.z) + 0.0625f * s1.y);
  o.w = pack_bf16(blo(v0.w) + blo(v1.w) + blo(v2.w) + blo(v3.w) + 0.0625f * s1.z,
                  bhi(v0.w) + bhi(v1.w) + bhi(v2.w) + bhi(v3.w) + 0.0625f * s1.w);
  *(uint4*)&AOb[i] = o;
}

extern "C" void kernel_launch(void* const* d_in, const int* in_sizes, int n_in,
                              void* d_out, int out_size, void* d_ws, size_t ws_size,
                              hipStream_t stream) {
  (void)in_sizes; (void)n_in; (void)out_size; (void)ws_size;
  const float* x = (const float*)d_in[0];
  const float* Wq = (const float*)d_in[1];
  const float* bq = (const float*)d_in[2];
  const float* Wk = (const float*)d_in[3];
  const float* bk = (const float*)d_in[4];
  const float* Wv = (const float*)d_in[5];
  const float* bv = (const float*)d_in[6];
  const float* Wo = (const float*)d_in[7];
  const float* bo = (const float*)d_in[8];
  float* out = (float*)d_out;
  char* ws = (char*)d_ws;

  const size_t MB = 1024 * 1024;
  unsigned short* xb  = (unsigned short*)(ws);            // 0-8MB; = AOP0 after projections
  unsigned short* Qb  = (unsigned short*)(ws + 8 * MB);   // 8-16; = AOb after attn
  unsigned short* Kb  = (unsigned short*)(ws + 16 * MB);  // 16-24
  unsigned short* Vb  = (unsigned short*)(ws + 24 * MB);  // 24-32; = AOP1 after transpose/vblk
  unsigned short* Vt  = (unsigned short*)(ws + 32 * MB);  // 32-40
  unsigned short* Wqt = (unsigned short*)(ws + 40 * MB);  // 40-42; Blk/Suf overlay after proj
  unsigned short* Wkt = (unsigned short*)(ws + 42 * MB);  // 42-44
  unsigned short* Wvt = (unsigned short*)(ws + 44 * MB);  // 44-46
  unsigned short* Wot = (unsigned short*)(ws + 46 * MB);  // 46-48
  unsigned short* AOP2 = (unsigned short*)(ws + 48 * MB); // 48-56
  unsigned short* AOP3 = (unsigned short*)(ws + 56 * MB); // 56-64
  float* Blk = (float*)(ws + 40 * MB);
  float* Suf = (float*)(ws + 40 * MB + 512 * 1024);
  unsigned short* AOP0 = xb;
  unsigned short* AOP1 = Vb;
  unsigned short* AOb = Qb;

  hipLaunchKernelGGL(wtrans, dim3(16, 16, 4), dim3(256), 0, stream,
                     Wq, Wk, Wv, Wo, Wqt, Wkt, Wvt, Wot);
  hipLaunchKernelGGL(xconv, dim3(2048), dim3(256), 0, stream, x, xb);
  hipLaunchKernelGGL((gemm_mfma<true>), dim3(8, 32, 3), dim3(256), 0, stream,
                     xb, Wqt, Wkt, Wvt, bq, bk, bv, (void*)Qb, (void*)Kb, (void*)Vb);
  hipLaunchKernelGGL(transpose_bf16, dim3(32, 16, 2), dim3(256), 0, stream, Vb, Vt);
  hipLaunchKernelGGL(vblk32, dim3(128), dim3(256), 0, stream, Vb, Blk);
  hipLaunchKernelGGL(vsuffix32, dim3(8), dim3(256), 0, stream, Blk, Suf);
  hipLaunchKernelGGL(attn_v7, dim3(4, 128, 2), dim3(512), 0, stream,
                     Qb, Kb, Vt, AOP0, AOP1, AOP2, AOP3);
  hipLaunchKernelGGL(aocvt, dim3(2048), dim3(256), 0, stream,
                     AOP0, AOP1, AOP2, AOP3, Suf, AOb);
  hipLaunchKernelGGL((gemm_mfma<false>), dim3(8, 32, 1), dim3(256), 0, stream,
                     AOb, Wot, Wot, Wot, bo, bo, bo, (void*)out, (void*)out, (void*)out);
}